// Round 8
// baseline (237.051 us; speedup 1.0000x reference)
//
#include <hip/hip_runtime.h>
#include <hip/hip_fp16.h>
#include <math.h>

#define NN 10000
#define NE 160000

typedef _Float16 half2v __attribute__((ext_vector_type(2)));
typedef _Float16 half8 __attribute__((ext_vector_type(8)));
typedef __attribute__((ext_vector_type(4))) float f32x4;

constexpr float SQRT3f    = 1.7320508075688772f;
constexpr float ISQRT3    = 0.57735026918962576f;
constexpr float ISQRT32   = 0.17677669529663687f;   // 1/sqrt(32)
constexpr float C_TP      = 0.14433756729740645f;   // 1/sqrt(48)
constexpr float CSIM      = 0.11180339887498949f;   // 1/sqrt(80)
constexpr float PREB      = 5.0596442562694074f;    // sqrt(2/2.5)*sqrt(32)
constexpr float PI_OVER_R = 1.2566370614359172f;    // pi/2.5
constexpr float INV_RMAX  = 0.4f;
constexpr float HKSC      = C_TP * ISQRT32;
constexpr float DEN_SCALE = 16777216.0f;            // 2^24
constexpr float DEN_INV   = 1.0f / 16777216.0f;
constexpr float OUT_SCALE = 8388608.0f;             // 2^23
constexpr float OUT_INV   = 1.0f / 8388608.0f;

__device__ __forceinline__ unsigned fkey(float f) {
  unsigned u = __float_as_uint(f);
  return (u & 0x80000000u) ? ~u : (u | 0x80000000u);
}
__device__ __forceinline__ float funkey(unsigned k) {
  return (k & 0x80000000u) ? __uint_as_float(k ^ 0x80000000u)
                           : __uint_as_float(~k);
}
__device__ __forceinline__ unsigned short f2h(float f) {
  return __half_as_ushort(__float2half(f));
}
__device__ __forceinline__ half2v pk2(float a, float b) {
#if defined(__has_builtin) && __has_builtin(__builtin_amdgcn_cvt_pkrtz)
  auto t = __builtin_amdgcn_cvt_pkrtz(a, b);
  half2v r; r[0] = t[0]; r[1] = t[1];
  return r;
#else
  half2v r; r[0] = (_Float16)a; r[1] = (_Float16)b;
  return r;
#endif
}
// A-fragment: element j=2i -> h4[i]*g0, j=2i+1 -> h4[i]*g1 (k = 2h' + u2)
__device__ __forceinline__ half8 mk_a(float4 h4, float g0, float g1) {
  union { half2v h2[4]; half8 h8; } u;
  u.h2[0] = pk2(h4.x * g0, h4.x * g1);
  u.h2[1] = pk2(h4.y * g0, h4.y * g1);
  u.h2[2] = pk2(h4.z * g0, h4.z * g1);
  u.h2[3] = pk2(h4.w * g0, h4.w * g1);
  return u.h8;
}

// ---- K0: build v-net B tiles (k=(h',u2)-interleaved) + W1 transposes ----
// Btg layout (shorts): [0,12288): main-low  tiles t=uq*2+H (uq<16), 12 cols:
//   addr = t*384 + w*32 + k,  h=16H+(k>>1), u=2uq+(k&1) (<32)
//   col w<8: orig u*8+w ; w in [8,12): 384+u*4+(w-8)
// [12288,16384): main-high tiles t=(uq-16)*2+H, 8 cols: 256+(u-32)*8+w
// [16384,18432): ot1 tiles t=up*2+H, 4 cols: 512+u'*4+w
__global__ void __launch_bounds__(256) k_prep(
    const float* __restrict__ w_vb1, const float* __restrict__ w_vb2,
    const float* __restrict__ w_kb1,
    float* __restrict__ W1vt, float* __restrict__ W1kt,
    unsigned short* __restrict__ Btg)
{
  int tid = blockIdx.x * 256 + threadIdx.x;
  if (tid < 12288) {
    int t = tid / 384, rem = tid % 384;
    int w = rem >> 5, k = rem & 31;
    int uq = t >> 1, H = t & 1;
    int h = 16 * H + (k >> 1), u = 2 * uq + (k & 1);
    int oc = (w < 8) ? (u * 8 + w) : (384 + u * 4 + (w - 8));
    Btg[tid] = f2h(w_vb2[h * 576 + oc]);
  } else if (tid < 16384) {
    int j = tid - 12288;
    int t = j >> 8, rem = j & 255;
    int w = rem >> 5, k = rem & 31;
    int uq = 16 + (t >> 1), H = t & 1;
    int h = 16 * H + (k >> 1), u = 2 * uq + (k & 1);
    Btg[tid] = f2h(w_vb2[h * 576 + 256 + (u - 32) * 8 + w]);
  } else if (tid < 18432) {
    int j = tid - 16384;
    int t = j >> 7, rem = j & 127;
    int w = rem >> 5, k = rem & 31;
    int up = t >> 1, H = t & 1;
    int h = 16 * H + (k >> 1), u2 = 2 * up + (k & 1);
    Btg[tid] = f2h(w_vb2[h * 576 + 512 + u2 * 4 + w]);
  } else if (tid < 19456) {
    int j = tid - 18432;
    int h = j >> 5, n = j & 31;
    W1vt[h * 32 + n] = w_vb1[n * 32 + h];
  } else if (tid < 20480) {
    int j = tid - 19456;
    int h = j >> 5, n = j & 31;
    W1kt[h * 32 + n] = w_kb1[n * 32 + h];
  }
}

// ---- K1n: per-node query projections folded with w_sim (unchanged) ----
__global__ void __launch_bounds__(256) k_node(
    const float* __restrict__ x, const float* __restrict__ w_q0,
    const float* __restrict__ w_q1, const float* __restrict__ w_sim0,
    const float* __restrict__ w_sim1,
    float* __restrict__ qs0, float* __restrict__ qs1)
{
  int n = blockIdx.x * 256 + threadIdx.x;
  if (n >= NN) return;
  float x0[32], x1f[48];
  const float4* xr = (const float4*)(x + 80 * n);
#pragma unroll
  for (int i = 0; i < 8; ++i) {
    float4 v = xr[i];
    x0[4*i]=v.x; x0[4*i+1]=v.y; x0[4*i+2]=v.z; x0[4*i+3]=v.w;
  }
#pragma unroll
  for (int i = 0; i < 12; ++i) {
    float4 v = xr[8 + i];
    x1f[4*i]=v.x; x1f[4*i+1]=v.y; x1f[4*i+2]=v.z; x1f[4*i+3]=v.w;
  }
  float q0[8];
#pragma unroll
  for (int w = 0; w < 8; ++w) {
    float a = 0.f;
#pragma unroll
    for (int u = 0; u < 32; ++u) a = fmaf(x0[u], w_q0[u * 8 + w], a);
    q0[w] = a * ISQRT32;
  }
  float q1[12];
#pragma unroll
  for (int w = 0; w < 4; ++w)
#pragma unroll
    for (int m = 0; m < 3; ++m) {
      float a = 0.f;
#pragma unroll
      for (int u = 0; u < 16; ++u) a = fmaf(x1f[3*u+m], w_q1[u*4+w], a);
      q1[w * 3 + m] = a * 0.25f;
    }
#pragma unroll
  for (int v = 0; v < 8; ++v) {
    float a = 0.f;
#pragma unroll
    for (int u = 0; u < 8; ++u) a = fmaf(w_sim0[u * 8 + v], q0[u], a);
    qs0[n * 8 + v] = CSIM * a;
  }
#pragma unroll
  for (int v = 0; v < 4; ++v)
#pragma unroll
    for (int m = 0; m < 3; ++m) {
      float a = 0.f;
#pragma unroll
      for (int u = 0; u < 4; ++u) a = fmaf(w_sim1[u*4+v], q1[u*3+m], a);
      qs1[n * 12 + v * 3 + m] = (CSIM * ISQRT3) * a;
    }
}

// ---- K2a: per-(node,h) hoisted logit tensors (unchanged from round 7) ----
template <int HALF>
__global__ void __launch_bounds__(256) k_nodeF(
    const float* __restrict__ x, const float* __restrict__ w_kb2,
    const float* __restrict__ qs0g, const float* __restrict__ qs1g,
    float* __restrict__ nodeF)
{
  __shared__ float W2f[16 * 577];
  __shared__ float ndl[16][100];

  const int tid = threadIdx.x;
  const int nb = blockIdx.x * 16;

#pragma unroll
  for (int i = 0; i < 36; ++i) {
    int idx = i * 256 + tid;
    int row = idx / 576, col = idx - row * 576;
    W2f[row * 577 + col] = w_kb2[(HALF * 16 + row) * 576 + col];
  }
  for (int j = tid; j < 1600; j += 256) {
    int nn = j / 100, jj = j - nn * 100;
    int n = nb + nn;
    float v;
    if (jj < 80)      v = x[80 * n + jj];
    else if (jj < 88) v = qs0g[8 * n + (jj - 80)];
    else              v = qs1g[12 * n + (jj - 88)];
    ndl[nn][jj] = v;
  }
  __syncthreads();

  const int nn = tid >> 4, hh = tid & 15;
  const float* Wh = W2f + hh * 577;
  const float* nd = ndl[nn];

  float t14 = 0.f;
#pragma unroll
  for (int a = 0; a < 32; ++a) {
    float tmp = 0.f;
#pragma unroll
    for (int v = 0; v < 8; ++v) tmp = fmaf(Wh[a * 8 + v], nd[80 + v], tmp);
    t14 = fmaf(tmp, nd[a], t14);
  }
#pragma unroll
  for (int a = 0; a < 16; ++a)
#pragma unroll
    for (int v = 0; v < 4; ++v) {
      float dotv = fmaf(nd[32 + 3*a], nd[88 + 3*v],
                   fmaf(nd[32 + 3*a + 1], nd[88 + 3*v + 1],
                        nd[32 + 3*a + 2] * nd[88 + 3*v + 2]));
      t14 = fmaf(Wh[512 + a * 4 + v], dotv, t14);
    }

  float F0 = 0.f, F1 = 0.f, F2 = 0.f;
#pragma unroll
  for (int a = 0; a < 16; ++a) {
    float q = 0.f;
#pragma unroll
    for (int v = 0; v < 8; ++v) q = fmaf(Wh[256 + a * 8 + v], nd[80 + v], q);
    F0 = fmaf(q, nd[32 + 3*a],     F0);
    F1 = fmaf(q, nd[32 + 3*a + 1], F1);
    F2 = fmaf(q, nd[32 + 3*a + 2], F2);
  }
  F0 *= ISQRT3; F1 *= ISQRT3; F2 *= ISQRT3;
#pragma unroll
  for (int v = 0; v < 4; ++v) {
    float rr = 0.f;
#pragma unroll
    for (int a = 0; a < 32; ++a) rr = fmaf(Wh[384 + a * 4 + v], nd[a], rr);
    F0 = fmaf(rr, nd[88 + 3*v],     F0);
    F1 = fmaf(rr, nd[88 + 3*v + 1], F1);
    F2 = fmaf(rr, nd[88 + 3*v + 2], F2);
  }

  const int n = nb + nn, h = HALF * 16 + hh;
  *(float4*)(nodeF + (size_t)(n * 32 + h) * 4) = make_float4(t14, F0, F1, F2);
}

// ---- fused per-edge kernel: geometry + bessel + fp32 hv + exact logits ----
// W1vt/W1kt read with wave-uniform indices -> scalar loads (K$), no LDS.
__global__ void __launch_bounds__(256) k_edgelogit(
    const float* __restrict__ pos,
    const int* __restrict__ esrc, const int* __restrict__ edst,
    const float* __restrict__ W1vt, const float* __restrict__ W1kt,
    const float* __restrict__ nodeF,
    float* __restrict__ hv, float* __restrict__ geom,
    float* __restrict__ rbuf,
    float* __restrict__ logits, unsigned* __restrict__ mkey)
{
  int e = blockIdx.x * 256 + threadIdx.x;
  if (e >= NE) return;
  int s = esrc[e], d = edst[e];
  float vx = pos[3*s]   - pos[3*d];
  float vy = pos[3*s+1] - pos[3*d+1];
  float vz = pos[3*s+2] - pos[3*d+2];
  float r = sqrtf(fmaf(vx, vx, fmaf(vy, vy, vz * vz)) + 1e-24f);
  float inv_r = 1.0f / r;

  float rb[32];
  {
    float sn, cth;
    sincosf(PI_OVER_R * r, &sn, &cth);
    float twoc = 2.0f * cth, pre = PREB * inv_r, snm1 = 0.0f;
#pragma unroll
    for (int n = 0; n < 32; ++n) {
      rb[n] = pre * sn;
      float t = fmaf(twoc, sn, -snm1);
      snm1 = sn; sn = t;
    }
  }
  float Yx = SQRT3f * vx * inv_r, Yy = SQRT3f * vy * inv_r, Yz = SQRT3f * vz * inv_r;
  float tc = 10.0f * (1.0f - r * INV_RMAX);
  float cut = (tc > 0.0f) ? __expf(-1.0f / tc) : 0.0f;
  *(float4*)(geom + 4 * e) = make_float4(Yx, Yy, Yz, cut);
  rbuf[e] = r;

  const float4* nf = (const float4*)(nodeF) + (size_t)s * 32;
  float sim = 0.f;
#pragma unroll 1
  for (int h = 0; h < 32; ++h) {
    const float* wvp = W1vt + h * 32;   // wave-uniform -> s_load
    const float* wkp = W1kt + h * 32;
    float av = 0.f, ak = 0.f;
#pragma unroll
    for (int n = 0; n < 32; ++n) {
      av = fmaf(rb[n], wvp[n], av);
      ak = fmaf(rb[n], wkp[n], ak);
    }
    av *= ISQRT32; ak *= ISQRT32;
    float hvv = av / (1.0f + __expf(-av)) * HKSC;
    hv[(size_t)e * 32 + h] = hvv;
    float hk = ak / (1.0f + __expf(-ak)) * HKSC;
    float4 f = nf[h];
    float S = fmaf(f.y, Yx, fmaf(f.z, Yy, fmaf(f.w, Yz, f.x)));
    sim = fmaf(hk, S, sim);
  }
  float lg = cut * sim;
  logits[e] = lg;
  atomicMax(mkey + s, fkey(lg));
}

// ---- softmax denominator (unchanged) ----
__global__ void __launch_bounds__(256) k_den(
    const float* __restrict__ logits, const int* __restrict__ esrc,
    const unsigned* __restrict__ mkey,
    float* __restrict__ exb, int* __restrict__ deni)
{
  int e = blockIdx.x * 256 + threadIdx.x;
  if (e >= NE) return;
  int s = esrc[e];
  float m = funkey(mkey[s]);
  float ex = expf(logits[e] - m);
  exb[e] = ex;
  atomicAdd(&deni[s], __float2int_rn(ex * DEN_SCALE));
}

// ---- K2v: v-path via A-scaled MFMA, direct C-layout (no butterfly) ----
__global__ void __launch_bounds__(256) k_tpv(
    const float* __restrict__ hv, const unsigned short* __restrict__ Btg,
    const float* __restrict__ x, const float* __restrict__ geom,
    const int* __restrict__ esrc, const int* __restrict__ edst,
    const float* __restrict__ exb, const int* __restrict__ deni,
    int* __restrict__ outi)
{
  __shared__ __align__(16) unsigned short Bls[18432];  // 36864 B
  __shared__ __align__(16) float g_lds[4][832];        // x0(32)+xdY(16), stride 52
  __shared__ __align__(16) float x1_lds[4][832];       // x1(48), stride 52

  const int l = threadIdx.x & 63, wv = threadIdx.x >> 6;
  const int G = l >> 4, c = l & 15;
  const int ebase = (blockIdx.x * 4 + wv) * 16;

  // stage B tiles (block-cooperative)
  {
    const uint4* src = (const uint4*)Btg;
    uint4* dst4 = (uint4*)Bls;
#pragma unroll
    for (int i = 0; i < 9; ++i)
      dst4[i * 256 + threadIdx.x] = src[i * 256 + threadIdx.x];
  }
  // stage x rows: 16 edges x 20 float4
#pragma unroll
  for (int i = 0; i < 5; ++i) {
    int idx = i * 64 + l;
    int ee = idx / 20, q = idx - 20 * ee;
    int ss = esrc[ebase + ee];
    float4 v = *(const float4*)(x + 80 * ss + 4 * q);
    if (q < 8) *(float4*)(&g_lds[wv][ee * 52 + 4 * q]) = v;
    else       *(float4*)(&x1_lds[wv][ee * 52 + 4 * q - 32]) = v;
  }
  // xdY -> g_lds cols 32..47
  {
    int ee = l >> 2, ug = l & 3;
    int ss = esrc[ebase + ee];
    float4 gm = *(const float4*)(geom + 4 * (ebase + ee));
    const float* xp = x + 80 * ss + 32 + 12 * ug;
    float4 p0 = *(const float4*)(xp);
    float4 p1 = *(const float4*)(xp + 4);
    float4 p2 = *(const float4*)(xp + 8);
    float4 o;
    o.x = ISQRT3 * fmaf(p0.x, gm.x, fmaf(p0.y, gm.y, p0.z * gm.z));
    o.y = ISQRT3 * fmaf(p0.w, gm.x, fmaf(p1.x, gm.y, p1.y * gm.z));
    o.z = ISQRT3 * fmaf(p1.z, gm.x, fmaf(p1.w, gm.y, p2.x * gm.z));
    o.w = ISQRT3 * fmaf(p2.y, gm.x, fmaf(p2.z, gm.y, p2.w * gm.z));
    *(float4*)(&g_lds[wv][ee * 52 + 32 + 4 * ug]) = o;
  }
  // per-lane hv (fp32): h = 4G..4G+3 (hA) and 16+4G..16+4G+3 (hB)
  const float4* hp = (const float4*)(hv + (size_t)(ebase + c) * 32);
  float4 hA = hp[G];
  float4 hB = hp[4 + G];

  __syncthreads();

  const int cw12 = min(c, 11) * 32;   // garbage cols never consumed
  const int cw8  = min(c, 7) * 32;
  const int cw4  = min(c, 3) * 32;
  const float* gl = &g_lds[wv][c * 52];
  const float* xl = &x1_lds[wv][c * 52];

  f32x4 accA = {0.f,0.f,0.f,0.f}, accB = {0.f,0.f,0.f,0.f};
  f32x4 accC = {0.f,0.f,0.f,0.f}, accD = {0.f,0.f,0.f,0.f};
  f32x4 am0  = {0.f,0.f,0.f,0.f}, am1  = {0.f,0.f,0.f,0.f}, am2 = {0.f,0.f,0.f,0.f};

  // main-low: u = 2uq+u2 in [0,32), g = x0
#pragma unroll
  for (int uq = 0; uq < 16; ++uq) {
    float g0 = gl[2 * uq], g1 = gl[2 * uq + 1];
    half8 a0 = mk_a(hA, g0, g1);
    half8 a1 = mk_a(hB, g0, g1);
    half8 b0 = *(const half8*)(Bls + (uq * 2    ) * 384 + cw12 + 8 * G);
    half8 b1 = *(const half8*)(Bls + (uq * 2 + 1) * 384 + cw12 + 8 * G);
    accA = __builtin_amdgcn_mfma_f32_16x16x32_f16(a0, b0, accA, 0, 0, 0);
    accB = __builtin_amdgcn_mfma_f32_16x16x32_f16(a1, b1, accB, 0, 0, 0);
  }
  // main-high: u in [32,48), g = xdY
#pragma unroll
  for (int uq = 0; uq < 8; ++uq) {
    float g0 = gl[32 + 2 * uq], g1 = gl[32 + 2 * uq + 1];
    half8 a0 = mk_a(hA, g0, g1);
    half8 a1 = mk_a(hB, g0, g1);
    half8 b0 = *(const half8*)(Bls + 12288 + (uq * 2    ) * 256 + cw8 + 8 * G);
    half8 b1 = *(const half8*)(Bls + 12288 + (uq * 2 + 1) * 256 + cw8 + 8 * G);
    accC = __builtin_amdgcn_mfma_f32_16x16x32_f16(a0, b0, accC, 0, 0, 0);
    accD = __builtin_amdgcn_mfma_f32_16x16x32_f16(a1, b1, accD, 0, 0, 0);
  }
  // ot1: u' = 2up+u2 in [0,16), A-scale by x1[3u'+m]
#pragma unroll
  for (int up = 0; up < 8; ++up) {
    half8 b0 = *(const half8*)(Bls + 16384 + (up * 2    ) * 128 + cw4 + 8 * G);
    half8 b1 = *(const half8*)(Bls + 16384 + (up * 2 + 1) * 128 + cw4 + 8 * G);
    {
      float xa = xl[6 * up + 0], xb = xl[6 * up + 3];
      am0 = __builtin_amdgcn_mfma_f32_16x16x32_f16(mk_a(hA, xa, xb), b0, am0, 0, 0, 0);
      am0 = __builtin_amdgcn_mfma_f32_16x16x32_f16(mk_a(hB, xa, xb), b1, am0, 0, 0, 0);
    }
    {
      float xa = xl[6 * up + 1], xb = xl[6 * up + 4];
      am1 = __builtin_amdgcn_mfma_f32_16x16x32_f16(mk_a(hA, xa, xb), b0, am1, 0, 0, 0);
      am1 = __builtin_amdgcn_mfma_f32_16x16x32_f16(mk_a(hB, xa, xb), b1, am1, 0, 0, 0);
    }
    {
      float xa = xl[6 * up + 2], xb = xl[6 * up + 5];
      am2 = __builtin_amdgcn_mfma_f32_16x16x32_f16(mk_a(hA, xa, xb), b0, am2, 0, 0, 0);
      am2 = __builtin_amdgcn_mfma_f32_16x16x32_f16(mk_a(hB, xa, xb), b1, am2, 0, 0, 0);
    }
  }

  // epilogue: lane c = output column; rows = edges 4G+r
  float tsum[4], out0v[4], s01w[4];
#pragma unroll
  for (int r = 0; r < 4; ++r) {
    tsum[r]  = accA[r] + accB[r];             // valid cols 0..11
    out0v[r] = tsum[r] + accC[r] + accD[r];   // valid cols 0..7
  }
#pragma unroll
  for (int r = 0; r < 4; ++r) s01w[r] = __shfl_xor(tsum[r], 8);  // c<4 gets s01

  int sr[4], dst[4]; float4 g4[4]; float a_[4];
#pragma unroll
  for (int r = 0; r < 4; ++r) {
    int eg = ebase + 4 * G + r;
    sr[r] = esrc[eg];
    dst[r] = edst[eg];
    g4[r] = *(const float4*)(geom + 4 * eg);
    float denf = (float)deni[sr[r]] * DEN_INV;
    a_[r] = sqrtf(fmaxf(exb[eg] / denf, 0.f)) * 0.03125f;
  }
  if (c < 8) {
#pragma unroll
    for (int r = 0; r < 4; ++r)
      atomicAdd(outi + 20 * dst[r] + c,
                __float2int_rn(a_[r] * out0v[r] * OUT_SCALE));
  }
  if (c < 4) {
#pragma unroll
    for (int r = 0; r < 4; ++r) {
      float vx_ = fmaf(s01w[r], g4[r].x, am0[r]);
      float vy_ = fmaf(s01w[r], g4[r].y, am1[r]);
      float vz_ = fmaf(s01w[r], g4[r].z, am2[r]);
      atomicAdd(outi + 20 * dst[r] + 8 + 3 * c + 0,
                __float2int_rn(a_[r] * vx_ * OUT_SCALE));
      atomicAdd(outi + 20 * dst[r] + 8 + 3 * c + 1,
                __float2int_rn(a_[r] * vy_ * OUT_SCALE));
      atomicAdd(outi + 20 * dst[r] + 8 + 3 * c + 2,
                __float2int_rn(a_[r] * vz_ * OUT_SCALE));
    }
  }
}

// ---- final int -> float conversion ----
__global__ void __launch_bounds__(256) k_out(
    const int* __restrict__ outi, float* __restrict__ out)
{
  int i = blockIdx.x * 256 + threadIdx.x;
  if (i < NN * 20) out[i] = (float)outi[i] * OUT_INV;
}

extern "C" void kernel_launch(void* const* d_in, const int* in_sizes, int n_in,
                              void* d_out, int out_size, void* d_ws, size_t ws_size,
                              hipStream_t stream)
{
  const float* x      = (const float*)d_in[0];
  const float* pos    = (const float*)d_in[1];
  const float* w_q0   = (const float*)d_in[2];
  const float* w_q1   = (const float*)d_in[3];
  const float* w_kb1  = (const float*)d_in[4];
  const float* w_kb2  = (const float*)d_in[5];
  const float* w_vb1  = (const float*)d_in[6];
  const float* w_vb2  = (const float*)d_in[7];
  const float* w_sim0 = (const float*)d_in[8];
  const float* w_sim1 = (const float*)d_in[9];
  const int*   eidx   = (const int*)d_in[10];
  const int* esrc = eidx;
  const int* edst = eidx + NE;
  float* out = (float*)d_out;

  float* ws      = (float*)d_ws;
  float* geom    = ws;                              // NE*4
  float* rbuf    = geom + (size_t)NE * 4;           // NE
  float* qs0     = rbuf + NE;                       // NN*8
  float* qs1     = qs0 + NN * 8;                    // NN*12
  float* logits  = qs1 + NN * 12;                   // NE
  float* exb     = logits + NE;                     // NE
  float* nodeF   = exb + NE;                        // NN*128
  int*   deni    = (int*)(nodeF + (size_t)NN * 128);// NN
  unsigned* mkey = (unsigned*)(deni + NN);          // NN
  int*   outi    = (int*)(mkey + NN);               // NN*20
  float* W1vt    = (float*)(outi + NN * 20);        // 1024
  float* W1kt    = W1vt + 1024;                     // 1024
  float* hv      = W1kt + 1024;                     // NE*32
  unsigned short* Btg = (unsigned short*)(hv + (size_t)NE * 32); // 18432 shorts

  // zero deni + mkey + outi (contiguous, 22*NN ints)
  hipMemsetAsync(deni, 0, (size_t)(NN * 22) * sizeof(int), stream);

  const int eb = (NE + 255) / 256;   // 625
  k_prep<<<dim3(80), dim3(256), 0, stream>>>(
      w_vb1, w_vb2, w_kb1, W1vt, W1kt, Btg);
  k_node<<<dim3((NN + 255) / 256), dim3(256), 0, stream>>>(
      x, w_q0, w_q1, w_sim0, w_sim1, qs0, qs1);
  k_nodeF<0><<<dim3(NN / 16), dim3(256), 0, stream>>>(
      x, w_kb2, qs0, qs1, nodeF);
  k_nodeF<1><<<dim3(NN / 16), dim3(256), 0, stream>>>(
      x, w_kb2, qs0, qs1, nodeF);
  k_edgelogit<<<dim3(eb), dim3(256), 0, stream>>>(
      pos, esrc, edst, W1vt, W1kt, nodeF, hv, geom, rbuf, logits, mkey);
  k_den<<<dim3(eb), dim3(256), 0, stream>>>(logits, esrc, mkey, exb, deni);
  k_tpv<<<dim3(NE / 64), dim3(256), 0, stream>>>(
      hv, Btg, x, geom, esrc, edst, exb, deni, outi);
  k_out<<<dim3((NN * 20 + 255) / 256), dim3(256), 0, stream>>>(outi, out);
}

// Round 9
// 199.476 us; speedup vs baseline: 1.1884x; 1.1884x over previous
//
#include <hip/hip_runtime.h>
#include <hip/hip_fp16.h>
#include <math.h>

#define NN 10000
#define NE 160000

typedef _Float16 half8 __attribute__((ext_vector_type(8)));
typedef __attribute__((ext_vector_type(4))) float f32x4;

constexpr float SQRT3f    = 1.7320508075688772f;
constexpr float ISQRT3    = 0.57735026918962576f;
constexpr float ISQRT32   = 0.17677669529663687f;   // 1/sqrt(32)
constexpr float C_TP      = 0.14433756729740645f;   // 1/sqrt(48)
constexpr float CSIM      = 0.11180339887498949f;   // 1/sqrt(80)
constexpr float PREB      = 5.0596442562694074f;    // sqrt(2/2.5)*sqrt(32)
constexpr float PI_OVER_R = 1.2566370614359172f;    // pi/2.5
constexpr float INV_RMAX  = 0.4f;
constexpr float HKSC      = C_TP * ISQRT32;
constexpr float DEN_SCALE = 16777216.0f;            // 2^24
constexpr float DEN_INV   = 1.0f / 16777216.0f;
constexpr float OUT_SCALE = 8388608.0f;             // 2^23
constexpr float OUT_INV   = 1.0f / 8388608.0f;

__device__ __forceinline__ unsigned fkey(float f) {
  unsigned u = __float_as_uint(f);
  return (u & 0x80000000u) ? ~u : (u | 0x80000000u);
}
__device__ __forceinline__ float funkey(unsigned k) {
  return (k & 0x80000000u) ? __uint_as_float(k ^ 0x80000000u)
                           : __uint_as_float(~k);
}
__device__ __forceinline__ unsigned short f2h(float f) {
  return __half_as_ushort(__float2half(f));
}

// w-major repacked column -> original W2 column. n in [0,640).
__device__ __forceinline__ int origcol(int n) {
  if (n >= 576) return 512 + (n - 576);
  int w = n / 48, u = n % 48;
  if (w < 8) return (u < 32) ? (u * 8 + w) : (256 + (u - 32) * 8 + w);
  return (u < 32) ? (384 + u * 4 + (w - 8)) : -1;
}

// ---- K0: v-net W2 fp16 repack (round-7 tile layout) + W1 transposes ----
__global__ void __launch_bounds__(256) k_prep(
    const float* __restrict__ w_vb1, const float* __restrict__ w_vb2,
    const float* __restrict__ w_kb1,
    float* __restrict__ W1vt, float* __restrict__ W1kt,
    unsigned short* __restrict__ Wtv)
{
  int tid = blockIdx.x * 256 + threadIdx.x;
  if (tid < 640 * 32) {
    int n = tid >> 5, h = tid & 31;
    int oc = origcol(n);
    float v = (oc >= 0) ? w_vb2[h * 576 + oc] : 0.0f;
    Wtv[n * 32 + h] = f2h(v);
  }
  if (tid < 1024) {
    int h = tid >> 5, n2 = tid & 31;
    W1vt[h * 32 + n2] = w_vb1[n2 * 32 + h];
  } else if (tid < 2048) {
    int j = tid - 1024;
    int h = j >> 5, n2 = j & 31;
    W1kt[h * 32 + n2] = w_kb1[n2 * 32 + h];
  }
}

// ---- K1n: per-node query projections folded with w_sim ----
__global__ void __launch_bounds__(256) k_node(
    const float* __restrict__ x, const float* __restrict__ w_q0,
    const float* __restrict__ w_q1, const float* __restrict__ w_sim0,
    const float* __restrict__ w_sim1,
    float* __restrict__ qs0, float* __restrict__ qs1)
{
  int n = blockIdx.x * 256 + threadIdx.x;
  if (n >= NN) return;
  float x0[32], x1f[48];
  const float4* xr = (const float4*)(x + 80 * n);
#pragma unroll
  for (int i = 0; i < 8; ++i) {
    float4 v = xr[i];
    x0[4*i]=v.x; x0[4*i+1]=v.y; x0[4*i+2]=v.z; x0[4*i+3]=v.w;
  }
#pragma unroll
  for (int i = 0; i < 12; ++i) {
    float4 v = xr[8 + i];
    x1f[4*i]=v.x; x1f[4*i+1]=v.y; x1f[4*i+2]=v.z; x1f[4*i+3]=v.w;
  }
  float q0[8];
#pragma unroll
  for (int w = 0; w < 8; ++w) {
    float a = 0.f;
#pragma unroll
    for (int u = 0; u < 32; ++u) a = fmaf(x0[u], w_q0[u * 8 + w], a);
    q0[w] = a * ISQRT32;
  }
  float q1[12];
#pragma unroll
  for (int w = 0; w < 4; ++w)
#pragma unroll
    for (int m = 0; m < 3; ++m) {
      float a = 0.f;
#pragma unroll
      for (int u = 0; u < 16; ++u) a = fmaf(x1f[3*u+m], w_q1[u*4+w], a);
      q1[w * 3 + m] = a * 0.25f;
    }
#pragma unroll
  for (int v = 0; v < 8; ++v) {
    float a = 0.f;
#pragma unroll
    for (int u = 0; u < 8; ++u) a = fmaf(w_sim0[u * 8 + v], q0[u], a);
    qs0[n * 8 + v] = CSIM * a;
  }
#pragma unroll
  for (int v = 0; v < 4; ++v)
#pragma unroll
    for (int m = 0; m < 3; ++m) {
      float a = 0.f;
#pragma unroll
      for (int u = 0; u < 4; ++u) a = fmaf(w_sim1[u*4+v], q1[u*3+m], a);
      qs1[n * 12 + v * 3 + m] = (CSIM * ISQRT3) * a;
    }
}

// ---- K2a: per-(node,h) hoisted logit tensors: t14 + F[3] ----
template <int HALF>
__global__ void __launch_bounds__(256) k_nodeF(
    const float* __restrict__ x, const float* __restrict__ w_kb2,
    const float* __restrict__ qs0g, const float* __restrict__ qs1g,
    float* __restrict__ nodeF)
{
  __shared__ float W2f[16 * 577];
  __shared__ float ndl[16][100];

  const int tid = threadIdx.x;
  const int nb = blockIdx.x * 16;

#pragma unroll
  for (int i = 0; i < 36; ++i) {
    int idx = i * 256 + tid;
    int row = idx / 576, col = idx - row * 576;
    W2f[row * 577 + col] = w_kb2[(HALF * 16 + row) * 576 + col];
  }
  for (int j = tid; j < 1600; j += 256) {
    int nn = j / 100, jj = j - nn * 100;
    int n = nb + nn;
    float v;
    if (jj < 80)      v = x[80 * n + jj];
    else if (jj < 88) v = qs0g[8 * n + (jj - 80)];
    else              v = qs1g[12 * n + (jj - 88)];
    ndl[nn][jj] = v;
  }
  __syncthreads();

  const int nn = tid >> 4, hh = tid & 15;
  const float* Wh = W2f + hh * 577;
  const float* nd = ndl[nn];

  float t14 = 0.f;
#pragma unroll
  for (int a = 0; a < 32; ++a) {
    float tmp = 0.f;
#pragma unroll
    for (int v = 0; v < 8; ++v) tmp = fmaf(Wh[a * 8 + v], nd[80 + v], tmp);
    t14 = fmaf(tmp, nd[a], t14);
  }
#pragma unroll
  for (int a = 0; a < 16; ++a)
#pragma unroll
    for (int v = 0; v < 4; ++v) {
      float dotv = fmaf(nd[32 + 3*a], nd[88 + 3*v],
                   fmaf(nd[32 + 3*a + 1], nd[88 + 3*v + 1],
                        nd[32 + 3*a + 2] * nd[88 + 3*v + 2]));
      t14 = fmaf(Wh[512 + a * 4 + v], dotv, t14);
    }

  float F0 = 0.f, F1 = 0.f, F2 = 0.f;
#pragma unroll
  for (int a = 0; a < 16; ++a) {
    float q = 0.f;
#pragma unroll
    for (int v = 0; v < 8; ++v) q = fmaf(Wh[256 + a * 8 + v], nd[80 + v], q);
    F0 = fmaf(q, nd[32 + 3*a],     F0);
    F1 = fmaf(q, nd[32 + 3*a + 1], F1);
    F2 = fmaf(q, nd[32 + 3*a + 2], F2);
  }
  F0 *= ISQRT3; F1 *= ISQRT3; F2 *= ISQRT3;
#pragma unroll
  for (int v = 0; v < 4; ++v) {
    float rr = 0.f;
#pragma unroll
    for (int a = 0; a < 32; ++a) rr = fmaf(Wh[384 + a * 4 + v], nd[a], rr);
    F0 = fmaf(rr, nd[88 + 3*v],     F0);
    F1 = fmaf(rr, nd[88 + 3*v + 1], F1);
    F2 = fmaf(rr, nd[88 + 3*v + 2], F2);
  }

  const int n = nb + nn, h = HALF * 16 + hh;
  *(float4*)(nodeF + (size_t)(n * 32 + h) * 4) = make_float4(t14, F0, F1, F2);
}

// ---- fused per-edge: geometry + bessel + fp16 hv (coalesced) + fp32 logits ----
// hv2 layout: [h2][NE] dwords (h = 2*h2, 2*h2+1) -> coalesced stores/loads.
__global__ void __launch_bounds__(256) k_edgelogit(
    const float* __restrict__ pos,
    const int* __restrict__ esrc, const int* __restrict__ edst,
    const float* __restrict__ W1vt, const float* __restrict__ W1kt,
    const float* __restrict__ nodeF,
    unsigned* __restrict__ hv2, float* __restrict__ geom,
    float* __restrict__ logits, unsigned* __restrict__ mkey)
{
  int e = blockIdx.x * 256 + threadIdx.x;
  if (e >= NE) return;
  int s = esrc[e], d = edst[e];
  float vx = pos[3*s]   - pos[3*d];
  float vy = pos[3*s+1] - pos[3*d+1];
  float vz = pos[3*s+2] - pos[3*d+2];
  float r = sqrtf(fmaf(vx, vx, fmaf(vy, vy, vz * vz)) + 1e-24f);
  float inv_r = 1.0f / r;

  float rb[32];
  {
    float sn, cth;
    sincosf(PI_OVER_R * r, &sn, &cth);
    float twoc = 2.0f * cth, pre = PREB * inv_r, snm1 = 0.0f;
#pragma unroll
    for (int n = 0; n < 32; ++n) {
      rb[n] = pre * sn;
      float t = fmaf(twoc, sn, -snm1);
      snm1 = sn; sn = t;
    }
  }
  float Yx = SQRT3f * vx * inv_r, Yy = SQRT3f * vy * inv_r, Yz = SQRT3f * vz * inv_r;
  float tc = 10.0f * (1.0f - r * INV_RMAX);
  float cut = (tc > 0.0f) ? __expf(-1.0f / tc) : 0.0f;
  *(float4*)(geom + 4 * e) = make_float4(Yx, Yy, Yz, cut);

  const float4* nf = (const float4*)(nodeF) + (size_t)s * 32;
  float sim = 0.f;
#pragma unroll 1
  for (int h2 = 0; h2 < 16; ++h2) {
    const float* wv0 = W1vt + (2 * h2) * 32;   // wave-uniform -> s_load
    const float* wv1 = wv0 + 32;
    const float* wk0 = W1kt + (2 * h2) * 32;
    const float* wk1 = wk0 + 32;
    float av0 = 0.f, av1 = 0.f, ak0 = 0.f, ak1 = 0.f;
#pragma unroll
    for (int n = 0; n < 32; ++n) {
      float rn = rb[n];
      av0 = fmaf(rn, wv0[n], av0);
      av1 = fmaf(rn, wv1[n], av1);
      ak0 = fmaf(rn, wk0[n], ak0);
      ak1 = fmaf(rn, wk1[n], ak1);
    }
    av0 *= ISQRT32; av1 *= ISQRT32; ak0 *= ISQRT32; ak1 *= ISQRT32;
    float hv0 = av0 / (1.0f + __expf(-av0)) * HKSC;
    float hv1 = av1 / (1.0f + __expf(-av1)) * HKSC;
    hv2[(size_t)h2 * NE + e] = (unsigned)f2h(hv0) | ((unsigned)f2h(hv1) << 16);
    float hk0 = ak0 / (1.0f + __expf(-ak0)) * HKSC;
    float hk1 = ak1 / (1.0f + __expf(-ak1)) * HKSC;
    float4 f0 = nf[2 * h2], f1 = nf[2 * h2 + 1];
    float S0 = fmaf(f0.y, Yx, fmaf(f0.z, Yy, fmaf(f0.w, Yz, f0.x)));
    float S1 = fmaf(f1.y, Yx, fmaf(f1.z, Yy, fmaf(f1.w, Yz, f1.x)));
    sim = fmaf(hk0, S0, fmaf(hk1, S1, sim));
  }
  float lg = cut * sim;
  logits[e] = lg;
  atomicMax(mkey + s, fkey(lg));
}

// ---- softmax denominator (int fixed-point, deterministic) ----
__global__ void __launch_bounds__(256) k_den(
    const float* __restrict__ logits, const int* __restrict__ esrc,
    const unsigned* __restrict__ mkey,
    float* __restrict__ exb, int* __restrict__ deni)
{
  int e = blockIdx.x * 256 + threadIdx.x;
  if (e >= NE) return;
  int s = esrc[e];
  float m = funkey(mkey[s]);
  float ex = expf(logits[e] - m);
  exb[e] = ex;
  atomicAdd(&deni[s], __float2int_rn(ex * DEN_SCALE));
}

// ---- K2v: round-7 MFMA v-path, fp16 LDS + hoisted g + coalesced hv ----
__global__ void __launch_bounds__(256) k_tpv(
    const unsigned* __restrict__ hv2, const unsigned short* __restrict__ Wtv,
    const float* __restrict__ x, const float* __restrict__ geom,
    const int* __restrict__ esrc, const int* __restrict__ edst,
    const float* __restrict__ exb, const int* __restrict__ deni,
    int* __restrict__ outi)
{
  __shared__ __align__(16) unsigned short Bls[18432];      // 36 tiles, 36864 B
  __shared__ __align__(16) _Float16 g_lds[4][16 * 52];     // x0|xdY, 6656 B
  __shared__ __align__(16) _Float16 x1_lds[4][16 * 52];    // x1, 6656 B

  const int l = threadIdx.x & 63, wv = threadIdx.x >> 6;
  const int G = l >> 4, c = l & 15;
  const int ebase = (blockIdx.x * 4 + wv) * 16;

  // stage B tiles (block-cooperative)
  {
    const uint4* src = (const uint4*)Wtv;
    uint4* dst4 = (uint4*)Bls;
#pragma unroll
    for (int i = 0; i < 9; ++i)
      dst4[i * 256 + threadIdx.x] = src[i * 256 + threadIdx.x];
  }
  // stage x rows as fp16: 16 edges x 20 float4 -> 4-half groups
  union H4 { _Float16 h[4]; unsigned long long u; };
#pragma unroll
  for (int i = 0; i < 5; ++i) {
    int idx = i * 64 + l;
    int ee = idx / 20, q = idx - 20 * ee;
    int ss = esrc[ebase + ee];
    float4 v = *(const float4*)(x + 80 * ss + 4 * q);
    H4 p; p.h[0] = (_Float16)v.x; p.h[1] = (_Float16)v.y;
    p.h[2] = (_Float16)v.z; p.h[3] = (_Float16)v.w;
    if (q < 8)
      *(unsigned long long*)(&g_lds[wv][ee * 52 + 4 * q]) = p.u;
    else
      *(unsigned long long*)(&x1_lds[wv][ee * 52 + 4 * q - 32]) = p.u;
  }
  // xdY -> g_lds halves 32..47
  {
    int ee = l >> 2, ug = l & 3;
    int ss = esrc[ebase + ee];
    float4 gm = *(const float4*)(geom + 4 * (ebase + ee));
    const float* xp = x + 80 * ss + 32 + 12 * ug;
    float4 p0 = *(const float4*)(xp);
    float4 p1 = *(const float4*)(xp + 4);
    float4 p2 = *(const float4*)(xp + 8);
    H4 o;
    o.h[0] = (_Float16)(ISQRT3 * fmaf(p0.x, gm.x, fmaf(p0.y, gm.y, p0.z * gm.z)));
    o.h[1] = (_Float16)(ISQRT3 * fmaf(p0.w, gm.x, fmaf(p1.x, gm.y, p1.y * gm.z)));
    o.h[2] = (_Float16)(ISQRT3 * fmaf(p1.z, gm.x, fmaf(p1.w, gm.y, p2.x * gm.z)));
    o.h[3] = (_Float16)(ISQRT3 * fmaf(p2.y, gm.x, fmaf(p2.z, gm.y, p2.w * gm.z)));
    *(unsigned long long*)(&g_lds[wv][ee * 52 + 32 + 4 * ug]) = o.u;
  }
  // A fragment: hv[edge ebase+c][h=8G..8G+7] via 4 coalesced dwords
  union { unsigned u[4]; half8 h8; } ua;
#pragma unroll
  for (int j = 0; j < 4; ++j)
    ua.u[j] = hv2[(size_t)(4 * G + j) * NE + ebase + c];
  half8 a8 = ua.h8;

  __syncthreads();

  // tail-tile B fragments from global (L2), after the barrier
  half8 bt[4];
#pragma unroll
  for (int t = 0; t < 4; ++t)
    bt[t] = *(const half8*)(Wtv + ((36 + t) * 16 + c) * 32 + 8 * G);

  // hoist the 12 g values (reused across the 12 w-columns)
  float gh[4][3];
#pragma unroll
  for (int r = 0; r < 4; ++r)
#pragma unroll
    for (int j = 0; j < 3; ++j)
      gh[r][j] = (float)g_lds[wv][(4 * G + r) * 52 + 16 * j + c];

  float vacc[4][12];
#pragma unroll
  for (int r = 0; r < 4; ++r)
#pragma unroll
    for (int w = 0; w < 12; ++w) vacc[r][w] = 0.0f;
  float ot1[4][3];
#pragma unroll
  for (int r = 0; r < 4; ++r) { ot1[r][0]=0.f; ot1[r][1]=0.f; ot1[r][2]=0.f; }

  const f32x4 zero4 = {0.f, 0.f, 0.f, 0.f};
  // 36 main tiles, B from LDS
#pragma unroll
  for (int t = 0; t < 36; ++t) {
    union { uint4 u; half8 h; } cvt;
    cvt.u = *(const uint4*)(Bls + (t * 16 + c) * 32 + 8 * G);
    f32x4 dd = __builtin_amdgcn_mfma_f32_16x16x32_f16(a8, cvt.h, zero4, 0, 0, 0);
    const int w = t / 3, j = t % 3;
#pragma unroll
    for (int r = 0; r < 4; ++r)
      vacc[r][w] = fmaf(dd[r], gh[r][j], vacc[r][w]);
  }
  // 4 tail tiles (10-path): lane-local epilogue
#pragma unroll
  for (int t = 0; t < 4; ++t) {
    f32x4 dd = __builtin_amdgcn_mfma_f32_16x16x32_f16(a8, bt[t], zero4, 0, 0, 0);
    const int u = 4 * t + (c >> 2);
#pragma unroll
    for (int r = 0; r < 4; ++r) {
      const _Float16* xp = &x1_lds[wv][(4 * G + r) * 52 + 3 * u];
      ot1[r][0] = fmaf(dd[r], (float)xp[0], ot1[r][0]);
      ot1[r][1] = fmaf(dd[r], (float)xp[1], ot1[r][1]);
      ot1[r][2] = fmaf(dd[r], (float)xp[2], ot1[r][2]);
    }
  }

  // butterfly over the 16 u-lanes
#pragma unroll
  for (int m = 1; m < 16; m <<= 1)
#pragma unroll
    for (int r = 0; r < 4; ++r)
#pragma unroll
      for (int w = 0; w < 12; ++w)
        vacc[r][w] += __shfl_xor(vacc[r][w], m);
  // ot1: reduce the u-quarter bits
#pragma unroll
  for (int m = 4; m < 16; m <<= 1)
#pragma unroll
    for (int r = 0; r < 4; ++r)
#pragma unroll
      for (int k = 0; k < 3; ++k)
        ot1[r][k] += __shfl_xor(ot1[r][k], m);

  // lane c keeps column w==c
  float treg[4] = {0.f, 0.f, 0.f, 0.f};
#pragma unroll
  for (int w = 0; w < 12; ++w)
    if (c == w) {
#pragma unroll
      for (int r = 0; r < 4; ++r) treg[r] = vacc[r][w];
    }

  int sr[4], dst[4]; float4 g4[4]; float a_[4];
#pragma unroll
  for (int r = 0; r < 4; ++r) {
    int eg = ebase + 4 * G + r;
    sr[r] = esrc[eg];
    dst[r] = edst[eg];
    g4[r] = *(const float4*)(geom + 4 * eg);
    float denf = (float)deni[sr[r]] * DEN_INV;
    a_[r] = sqrtf(fmaxf(exb[eg] / denf, 0.f)) * 0.03125f;
  }
  float s01w[4];
#pragma unroll
  for (int r = 0; r < 4; ++r) s01w[r] = __shfl_xor(treg[r], 8);
  if (c < 8) {
#pragma unroll
    for (int r = 0; r < 4; ++r)
      atomicAdd(outi + 20 * dst[r] + c,
                __float2int_rn(a_[r] * treg[r] * OUT_SCALE));
  }
  if (c < 4) {
#pragma unroll
    for (int r = 0; r < 4; ++r) {
      float vx_ = fmaf(s01w[r], g4[r].x, ot1[r][0]);
      float vy_ = fmaf(s01w[r], g4[r].y, ot1[r][1]);
      float vz_ = fmaf(s01w[r], g4[r].z, ot1[r][2]);
      atomicAdd(outi + 20 * dst[r] + 8 + 3 * c + 0,
                __float2int_rn(a_[r] * vx_ * OUT_SCALE));
      atomicAdd(outi + 20 * dst[r] + 8 + 3 * c + 1,
                __float2int_rn(a_[r] * vy_ * OUT_SCALE));
      atomicAdd(outi + 20 * dst[r] + 8 + 3 * c + 2,
                __float2int_rn(a_[r] * vz_ * OUT_SCALE));
    }
  }
}

// ---- final int -> float conversion ----
__global__ void __launch_bounds__(256) k_out(
    const int* __restrict__ outi, float* __restrict__ out)
{
  int i = blockIdx.x * 256 + threadIdx.x;
  if (i < NN * 20) out[i] = (float)outi[i] * OUT_INV;
}

extern "C" void kernel_launch(void* const* d_in, const int* in_sizes, int n_in,
                              void* d_out, int out_size, void* d_ws, size_t ws_size,
                              hipStream_t stream)
{
  const float* x      = (const float*)d_in[0];
  const float* pos    = (const float*)d_in[1];
  const float* w_q0   = (const float*)d_in[2];
  const float* w_q1   = (const float*)d_in[3];
  const float* w_kb1  = (const float*)d_in[4];
  const float* w_kb2  = (const float*)d_in[5];
  const float* w_vb1  = (const float*)d_in[6];
  const float* w_vb2  = (const float*)d_in[7];
  const float* w_sim0 = (const float*)d_in[8];
  const float* w_sim1 = (const float*)d_in[9];
  const int*   eidx   = (const int*)d_in[10];
  const int* esrc = eidx;
  const int* edst = eidx + NE;
  float* out = (float*)d_out;

  float* ws      = (float*)d_ws;
  float* geom    = ws;                               // NE*4
  float* qs0     = geom + (size_t)NE * 4;            // NN*8
  float* qs1     = qs0 + NN * 8;                     // NN*12
  float* logits  = qs1 + NN * 12;                    // NE
  float* exb     = logits + NE;                      // NE
  float* nodeF   = exb + NE;                         // NN*128
  float* W1vt    = nodeF + (size_t)NN * 128;         // 1024
  float* W1kt    = W1vt + 1024;                      // 1024
  int*   deni    = (int*)(W1kt + 1024);              // NN
  unsigned* mkey = (unsigned*)(deni + NN);           // NN
  int*   outi    = (int*)(mkey + NN);                // NN*20
  unsigned* hv2  = (unsigned*)(outi + NN * 20);      // 16*NE dwords
  unsigned short* Wtv = (unsigned short*)(hv2 + (size_t)16 * NE); // 640*32

  // zero deni + mkey + outi (contiguous, 22*NN ints)
  hipMemsetAsync(deni, 0, (size_t)(NN * 22) * sizeof(int), stream);

  const int eb = (NE + 255) / 256;   // 625
  k_prep<<<dim3(80), dim3(256), 0, stream>>>(
      w_vb1, w_vb2, w_kb1, W1vt, W1kt, Wtv);
  k_node<<<dim3((NN + 255) / 256), dim3(256), 0, stream>>>(
      x, w_q0, w_q1, w_sim0, w_sim1, qs0, qs1);
  k_nodeF<0><<<dim3(NN / 16), dim3(256), 0, stream>>>(
      x, w_kb2, qs0, qs1, nodeF);
  k_nodeF<1><<<dim3(NN / 16), dim3(256), 0, stream>>>(
      x, w_kb2, qs0, qs1, nodeF);
  k_edgelogit<<<dim3(eb), dim3(256), 0, stream>>>(
      pos, esrc, edst, W1vt, W1kt, nodeF, hv2, geom, logits, mkey);
  k_den<<<dim3(eb), dim3(256), 0, stream>>>(logits, esrc, mkey, exb, deni);
  k_tpv<<<dim3(NE / 64), dim3(256), 0, stream>>>(
      hv2, Wtv, x, geom, esrc, edst, exb, deni, outi);
  k_out<<<dim3((NN * 20 + 255) / 256), dim3(256), 0, stream>>>(outi, out);
}

// Round 10
// 190.733 us; speedup vs baseline: 1.2428x; 1.0458x over previous
//
#include <hip/hip_runtime.h>
#include <hip/hip_fp16.h>
#include <math.h>

#define NN 10000
#define NE 160000

typedef _Float16 half8 __attribute__((ext_vector_type(8)));
typedef __attribute__((ext_vector_type(4))) float f32x4;

constexpr float SQRT3f    = 1.7320508075688772f;
constexpr float ISQRT3    = 0.57735026918962576f;
constexpr float ISQRT32   = 0.17677669529663687f;   // 1/sqrt(32)
constexpr float C_TP      = 0.14433756729740645f;   // 1/sqrt(48)
constexpr float CSIM      = 0.11180339887498949f;   // 1/sqrt(80)
constexpr float PREB      = 5.0596442562694074f;    // sqrt(2/2.5)*sqrt(32)
constexpr float PI_OVER_R = 1.2566370614359172f;    // pi/2.5
constexpr float INV_RMAX  = 0.4f;
constexpr float HKSC      = C_TP * ISQRT32;
constexpr float DEN_SCALE = 16777216.0f;            // 2^24
constexpr float DEN_INV   = 1.0f / 16777216.0f;
constexpr float OUT_SCALE = 8388608.0f;             // 2^23
constexpr float OUT_INV   = 1.0f / 8388608.0f;

__device__ __forceinline__ unsigned fkey(float f) {
  unsigned u = __float_as_uint(f);
  return (u & 0x80000000u) ? ~u : (u | 0x80000000u);
}
__device__ __forceinline__ float funkey(unsigned k) {
  return (k & 0x80000000u) ? __uint_as_float(k ^ 0x80000000u)
                           : __uint_as_float(~k);
}
__device__ __forceinline__ unsigned short f2h(float f) {
  return __half_as_ushort(__float2half(f));
}

// w-major repacked column -> original W2 column. n in [0,640).
__device__ __forceinline__ int origcol(int n) {
  if (n >= 576) return 512 + (n - 576);
  int w = n / 48, u = n % 48;
  if (w < 8) return (u < 32) ? (u * 8 + w) : (256 + (u - 32) * 8 + w);
  return (u < 32) ? (384 + u * 4 + (w - 8)) : -1;
}

// ---- K0: fused setup: weight prep (blocks 0..79) + node queries (80..119) ----
__global__ void __launch_bounds__(256) k_setup(
    const float* __restrict__ w_vb1, const float* __restrict__ w_vb2,
    const float* __restrict__ w_kb1,
    const float* __restrict__ x, const float* __restrict__ w_q0,
    const float* __restrict__ w_q1, const float* __restrict__ w_sim0,
    const float* __restrict__ w_sim1,
    float* __restrict__ W1vt, float* __restrict__ W1kt,
    unsigned short* __restrict__ Wtv,
    float* __restrict__ qs0, float* __restrict__ qs1)
{
  if (blockIdx.x < 80) {
    int tid = blockIdx.x * 256 + threadIdx.x;
    if (tid < 640 * 32) {
      int n = tid >> 5, h = tid & 31;
      int oc = origcol(n);
      float v = (oc >= 0) ? w_vb2[h * 576 + oc] : 0.0f;
      Wtv[n * 32 + h] = f2h(v);
    }
    if (tid < 1024) {
      int h = tid >> 5, n2 = tid & 31;
      W1vt[h * 32 + n2] = w_vb1[n2 * 32 + h];
    } else if (tid < 2048) {
      int j = tid - 1024;
      int h = j >> 5, n2 = j & 31;
      W1kt[h * 32 + n2] = w_kb1[n2 * 32 + h];
    }
    return;
  }
  int n = (blockIdx.x - 80) * 256 + threadIdx.x;
  if (n >= NN) return;
  float x0[32], x1f[48];
  const float4* xr = (const float4*)(x + 80 * n);
#pragma unroll
  for (int i = 0; i < 8; ++i) {
    float4 v = xr[i];
    x0[4*i]=v.x; x0[4*i+1]=v.y; x0[4*i+2]=v.z; x0[4*i+3]=v.w;
  }
#pragma unroll
  for (int i = 0; i < 12; ++i) {
    float4 v = xr[8 + i];
    x1f[4*i]=v.x; x1f[4*i+1]=v.y; x1f[4*i+2]=v.z; x1f[4*i+3]=v.w;
  }
  float q0[8];
#pragma unroll
  for (int w = 0; w < 8; ++w) {
    float a = 0.f;
#pragma unroll
    for (int u = 0; u < 32; ++u) a = fmaf(x0[u], w_q0[u * 8 + w], a);
    q0[w] = a * ISQRT32;
  }
  float q1[12];
#pragma unroll
  for (int w = 0; w < 4; ++w)
#pragma unroll
    for (int m = 0; m < 3; ++m) {
      float a = 0.f;
#pragma unroll
      for (int u = 0; u < 16; ++u) a = fmaf(x1f[3*u+m], w_q1[u*4+w], a);
      q1[w * 3 + m] = a * 0.25f;
    }
#pragma unroll
  for (int v = 0; v < 8; ++v) {
    float a = 0.f;
#pragma unroll
    for (int u = 0; u < 8; ++u) a = fmaf(w_sim0[u * 8 + v], q0[u], a);
    qs0[n * 8 + v] = CSIM * a;
  }
#pragma unroll
  for (int v = 0; v < 4; ++v)
#pragma unroll
    for (int m = 0; m < 3; ++m) {
      float a = 0.f;
#pragma unroll
      for (int u = 0; u < 4; ++u) a = fmaf(w_sim1[u*4+v], q1[u*3+m], a);
      qs1[n * 12 + v * 3 + m] = (CSIM * ISQRT3) * a;
    }
}

// ---- K2a: per-(node,h) hoisted logit tensors; both halves in one launch ----
__global__ void __launch_bounds__(256) k_nodeF(
    const float* __restrict__ x, const float* __restrict__ w_kb2,
    const float* __restrict__ qs0g, const float* __restrict__ qs1g,
    float* __restrict__ nodeF)
{
  __shared__ float W2f[16 * 577];
  __shared__ float ndl[16][100];

  const int tid = threadIdx.x;
  const int HALF = (blockIdx.x >= 625) ? 1 : 0;
  const int nb = (blockIdx.x - HALF * 625) * 16;

#pragma unroll
  for (int i = 0; i < 36; ++i) {
    int idx = i * 256 + tid;
    int row = idx / 576, col = idx - row * 576;
    W2f[row * 577 + col] = w_kb2[(HALF * 16 + row) * 576 + col];
  }
  for (int j = tid; j < 1600; j += 256) {
    int nn = j / 100, jj = j - nn * 100;
    int n = nb + nn;
    float v;
    if (jj < 80)      v = x[80 * n + jj];
    else if (jj < 88) v = qs0g[8 * n + (jj - 80)];
    else              v = qs1g[12 * n + (jj - 88)];
    ndl[nn][jj] = v;
  }
  __syncthreads();

  const int nn = tid >> 4, hh = tid & 15;
  const float* Wh = W2f + hh * 577;
  const float* nd = ndl[nn];

  float t14 = 0.f;
#pragma unroll
  for (int a = 0; a < 32; ++a) {
    float tmp = 0.f;
#pragma unroll
    for (int v = 0; v < 8; ++v) tmp = fmaf(Wh[a * 8 + v], nd[80 + v], tmp);
    t14 = fmaf(tmp, nd[a], t14);
  }
#pragma unroll
  for (int a = 0; a < 16; ++a)
#pragma unroll
    for (int v = 0; v < 4; ++v) {
      float dotv = fmaf(nd[32 + 3*a], nd[88 + 3*v],
                   fmaf(nd[32 + 3*a + 1], nd[88 + 3*v + 1],
                        nd[32 + 3*a + 2] * nd[88 + 3*v + 2]));
      t14 = fmaf(Wh[512 + a * 4 + v], dotv, t14);
    }

  float F0 = 0.f, F1 = 0.f, F2 = 0.f;
#pragma unroll
  for (int a = 0; a < 16; ++a) {
    float q = 0.f;
#pragma unroll
    for (int v = 0; v < 8; ++v) q = fmaf(Wh[256 + a * 8 + v], nd[80 + v], q);
    F0 = fmaf(q, nd[32 + 3*a],     F0);
    F1 = fmaf(q, nd[32 + 3*a + 1], F1);
    F2 = fmaf(q, nd[32 + 3*a + 2], F2);
  }
  F0 *= ISQRT3; F1 *= ISQRT3; F2 *= ISQRT3;
#pragma unroll
  for (int v = 0; v < 4; ++v) {
    float rr = 0.f;
#pragma unroll
    for (int a = 0; a < 32; ++a) rr = fmaf(Wh[384 + a * 4 + v], nd[a], rr);
    F0 = fmaf(rr, nd[88 + 3*v],     F0);
    F1 = fmaf(rr, nd[88 + 3*v + 1], F1);
    F2 = fmaf(rr, nd[88 + 3*v + 2], F2);
  }

  const int n = nb + nn, h = HALF * 16 + hh;
  *(float4*)(nodeF + (size_t)(n * 32 + h) * 4) = make_float4(t14, F0, F1, F2);
}

// ---- fused per-edge: geometry + bessel + fp16 hv (coalesced) + fp32 logits ----
__global__ void __launch_bounds__(256) k_edgelogit(
    const float* __restrict__ pos,
    const int* __restrict__ esrc, const int* __restrict__ edst,
    const float* __restrict__ W1vt, const float* __restrict__ W1kt,
    const float* __restrict__ nodeF,
    unsigned* __restrict__ hv2, float* __restrict__ geom,
    float* __restrict__ logits, unsigned* __restrict__ mkey)
{
  int e = blockIdx.x * 256 + threadIdx.x;
  if (e >= NE) return;
  int s = esrc[e], d = edst[e];
  float vx = pos[3*s]   - pos[3*d];
  float vy = pos[3*s+1] - pos[3*d+1];
  float vz = pos[3*s+2] - pos[3*d+2];
  float r = sqrtf(fmaf(vx, vx, fmaf(vy, vy, vz * vz)) + 1e-24f);
  float inv_r = 1.0f / r;

  float rb[32];
  {
    float sn, cth;
    sincosf(PI_OVER_R * r, &sn, &cth);
    float twoc = 2.0f * cth, pre = PREB * inv_r, snm1 = 0.0f;
#pragma unroll
    for (int n = 0; n < 32; ++n) {
      rb[n] = pre * sn;
      float t = fmaf(twoc, sn, -snm1);
      snm1 = sn; sn = t;
    }
  }
  float Yx = SQRT3f * vx * inv_r, Yy = SQRT3f * vy * inv_r, Yz = SQRT3f * vz * inv_r;
  float tc = 10.0f * (1.0f - r * INV_RMAX);
  float cut = (tc > 0.0f) ? __expf(-1.0f / tc) : 0.0f;
  *(float4*)(geom + 4 * e) = make_float4(Yx, Yy, Yz, cut);

  const float4* nf = (const float4*)(nodeF) + (size_t)s * 32;
  float sim = 0.f;
#pragma unroll 1
  for (int h2 = 0; h2 < 16; ++h2) {
    const float* wv0 = W1vt + (2 * h2) * 32;   // wave-uniform -> s_load
    const float* wv1 = wv0 + 32;
    const float* wk0 = W1kt + (2 * h2) * 32;
    const float* wk1 = wk0 + 32;
    float av0 = 0.f, av1 = 0.f, ak0 = 0.f, ak1 = 0.f;
#pragma unroll
    for (int n = 0; n < 32; ++n) {
      float rn = rb[n];
      av0 = fmaf(rn, wv0[n], av0);
      av1 = fmaf(rn, wv1[n], av1);
      ak0 = fmaf(rn, wk0[n], ak0);
      ak1 = fmaf(rn, wk1[n], ak1);
    }
    av0 *= ISQRT32; av1 *= ISQRT32; ak0 *= ISQRT32; ak1 *= ISQRT32;
    float hv0 = av0 / (1.0f + __expf(-av0)) * HKSC;
    float hv1 = av1 / (1.0f + __expf(-av1)) * HKSC;
    hv2[(size_t)h2 * NE + e] = (unsigned)f2h(hv0) | ((unsigned)f2h(hv1) << 16);
    float hk0 = ak0 / (1.0f + __expf(-ak0)) * HKSC;
    float hk1 = ak1 / (1.0f + __expf(-ak1)) * HKSC;
    float4 f0 = nf[2 * h2], f1 = nf[2 * h2 + 1];
    float S0 = fmaf(f0.y, Yx, fmaf(f0.z, Yy, fmaf(f0.w, Yz, f0.x)));
    float S1 = fmaf(f1.y, Yx, fmaf(f1.z, Yy, fmaf(f1.w, Yz, f1.x)));
    sim = fmaf(hk0, S0, fmaf(hk1, S1, sim));
  }
  float lg = cut * sim;
  logits[e] = lg;
  atomicMax(mkey + s, fkey(lg));
}

// ---- softmax denominator (int fixed-point, deterministic) ----
__global__ void __launch_bounds__(256) k_den(
    const float* __restrict__ logits, const int* __restrict__ esrc,
    const unsigned* __restrict__ mkey,
    float* __restrict__ exb, int* __restrict__ deni)
{
  int e = blockIdx.x * 256 + threadIdx.x;
  if (e >= NE) return;
  int s = esrc[e];
  float m = funkey(mkey[s]);
  float ex = expf(logits[e] - m);
  exb[e] = ex;
  atomicAdd(&deni[s], __float2int_rn(ex * DEN_SCALE));
}

// ---- K2v: round-7 MFMA v-path (fp32 LDS, butterfly), hv via 4 dwords ----
__global__ void __launch_bounds__(256) k_tpv(
    const unsigned* __restrict__ hv2, const unsigned short* __restrict__ Wtv,
    const float* __restrict__ x, const float* __restrict__ geom,
    const int* __restrict__ esrc, const int* __restrict__ edst,
    const float* __restrict__ exb, const int* __restrict__ deni,
    int* __restrict__ outi)
{
  __shared__ __align__(16) uint4  wlds4[2304];        // 36 tiles, 36864 B
  __shared__ __align__(16) float g_lds[4][16 * 52];   // x0 | xdYs
  __shared__ __align__(16) float x1_lds[4][16 * 52];  // x1 (48 floats)

  const int l = threadIdx.x & 63, wv = threadIdx.x >> 6;
  const int tile = blockIdx.x * 4 + wv;
  const int G = l >> 4, c = l & 15;
  const int ebase = tile * 16;

  // stage main-tile weights (block-cooperative)
  const uint4* Wt4 = (const uint4*)Wtv;
#pragma unroll
  for (int i = 0; i < 9; ++i) {
    int chunk = i * 256 + threadIdx.x;
    wlds4[chunk] = Wt4[chunk];
  }

  // stage x rows: 16 edges x 20 float4 (x0 -> g_lds, x1 -> x1_lds)
#pragma unroll
  for (int i = 0; i < 5; ++i) {
    int idx = i * 64 + l;
    int ee = idx / 20, q = idx - 20 * ee;
    int ss = esrc[ebase + ee];
    float4 v = *(const float4*)(x + 80 * ss + 4 * q);
    if (q < 8)
      *(float4*)(&g_lds[wv][ee * 52 + 4 * q]) = v;
    else
      *(float4*)(&x1_lds[wv][ee * 52 + 4 * q - 32]) = v;
  }

  // xdYs -> g_lds cols 32..47
  {
    int ee = l >> 2, ug = l & 3;
    int ss = esrc[ebase + ee];
    float4 gm = *(const float4*)(geom + 4 * (ebase + ee));
    const float* xp = x + 80 * ss + 32 + 12 * ug;
    float4 p0 = *(const float4*)(xp);
    float4 p1 = *(const float4*)(xp + 4);
    float4 p2 = *(const float4*)(xp + 8);
    float4 o;
    o.x = ISQRT3 * fmaf(p0.x, gm.x, fmaf(p0.y, gm.y, p0.z * gm.z));
    o.y = ISQRT3 * fmaf(p0.w, gm.x, fmaf(p1.x, gm.y, p1.y * gm.z));
    o.z = ISQRT3 * fmaf(p1.z, gm.x, fmaf(p1.w, gm.y, p2.x * gm.z));
    o.w = ISQRT3 * fmaf(p2.y, gm.x, fmaf(p2.z, gm.y, p2.w * gm.z));
    *(float4*)(&g_lds[wv][ee * 52 + 32 + 4 * ug]) = o;
  }

  // A fragment: hv[edge ebase+c][h=8G..8G+7] via 4 coalesced dwords
  union { unsigned u[4]; half8 h8; } ua;
#pragma unroll
  for (int j = 0; j < 4; ++j)
    ua.u[j] = hv2[(size_t)(4 * G + j) * NE + ebase + c];
  half8 a8 = ua.h8;

  __syncthreads();

  // tail-tile B fragments from global (L2-resident), after the barrier
  half8 bt[4];
#pragma unroll
  for (int t = 0; t < 4; ++t)
    bt[t] = *(const half8*)(Wtv + ((36 + t) * 16 + c) * 32 + 8 * G);

  float vacc[4][12];
#pragma unroll
  for (int r = 0; r < 4; ++r)
#pragma unroll
    for (int w = 0; w < 12; ++w) vacc[r][w] = 0.0f;
  float ot1[4][3];
#pragma unroll
  for (int r = 0; r < 4; ++r) { ot1[r][0]=0.f; ot1[r][1]=0.f; ot1[r][2]=0.f; }

  const f32x4 zero4 = {0.f, 0.f, 0.f, 0.f};
  // 36 main tiles, B from LDS
#pragma unroll
  for (int t = 0; t < 36; ++t) {
    union { uint4 u; half8 h; } cvt;
    cvt.u = wlds4[(t * 16 + c) * 4 + G];
    f32x4 dd = __builtin_amdgcn_mfma_f32_16x16x32_f16(a8, cvt.h, zero4, 0, 0, 0);
    const int w = t / 3, u0 = (t % 3) * 16;
#pragma unroll
    for (int r = 0; r < 4; ++r)
      vacc[r][w] = fmaf(dd[r], g_lds[wv][(4 * G + r) * 52 + u0 + c], vacc[r][w]);
  }
  // 4 tail tiles (10-path): lane-local epilogue
#pragma unroll
  for (int t = 0; t < 4; ++t) {
    f32x4 dd = __builtin_amdgcn_mfma_f32_16x16x32_f16(a8, bt[t], zero4, 0, 0, 0);
    const int u = 4 * t + (c >> 2);
#pragma unroll
    for (int r = 0; r < 4; ++r) {
      const float* xp = &x1_lds[wv][(4 * G + r) * 52 + 3 * u];
      ot1[r][0] = fmaf(dd[r], xp[0], ot1[r][0]);
      ot1[r][1] = fmaf(dd[r], xp[1], ot1[r][1]);
      ot1[r][2] = fmaf(dd[r], xp[2], ot1[r][2]);
    }
  }

  // butterfly over the 16 u-lanes
#pragma unroll
  for (int m = 1; m < 16; m <<= 1)
#pragma unroll
    for (int r = 0; r < 4; ++r)
#pragma unroll
      for (int w = 0; w < 12; ++w)
        vacc[r][w] += __shfl_xor(vacc[r][w], m);
  // ot1: reduce the u-quarter bits
#pragma unroll
  for (int m = 4; m < 16; m <<= 1)
#pragma unroll
    for (int r = 0; r < 4; ++r)
#pragma unroll
      for (int k = 0; k < 3; ++k)
        ot1[r][k] += __shfl_xor(ot1[r][k], m);

  // lane c keeps column w==c
  float treg[4] = {0.f, 0.f, 0.f, 0.f};
#pragma unroll
  for (int w = 0; w < 12; ++w)
    if (c == w) {
#pragma unroll
      for (int r = 0; r < 4; ++r) treg[r] = vacc[r][w];
    }

  int sr[4], dst[4]; float4 g4[4]; float a_[4];
#pragma unroll
  for (int r = 0; r < 4; ++r) {
    int eg = ebase + 4 * G + r;
    sr[r] = esrc[eg];
    dst[r] = edst[eg];
    g4[r] = *(const float4*)(geom + 4 * eg);
    float denf = (float)deni[sr[r]] * DEN_INV;
    a_[r] = sqrtf(fmaxf(exb[eg] / denf, 0.f)) * 0.03125f;
  }
  float s01w[4];
#pragma unroll
  for (int r = 0; r < 4; ++r) s01w[r] = __shfl_xor(treg[r], 8);
  if (c < 8) {
#pragma unroll
    for (int r = 0; r < 4; ++r)
      atomicAdd(outi + 20 * dst[r] + c,
                __float2int_rn(a_[r] * treg[r] * OUT_SCALE));
  }
  if (c < 4) {
#pragma unroll
    for (int r = 0; r < 4; ++r) {
      float vx_ = fmaf(s01w[r], g4[r].x, ot1[r][0]);
      float vy_ = fmaf(s01w[r], g4[r].y, ot1[r][1]);
      float vz_ = fmaf(s01w[r], g4[r].z, ot1[r][2]);
      atomicAdd(outi + 20 * dst[r] + 8 + 3 * c + 0,
                __float2int_rn(a_[r] * vx_ * OUT_SCALE));
      atomicAdd(outi + 20 * dst[r] + 8 + 3 * c + 1,
                __float2int_rn(a_[r] * vy_ * OUT_SCALE));
      atomicAdd(outi + 20 * dst[r] + 8 + 3 * c + 2,
                __float2int_rn(a_[r] * vz_ * OUT_SCALE));
    }
  }
}

// ---- final int -> float conversion ----
__global__ void __launch_bounds__(256) k_out(
    const int* __restrict__ outi, float* __restrict__ out)
{
  int i = blockIdx.x * 256 + threadIdx.x;
  if (i < NN * 20) out[i] = (float)outi[i] * OUT_INV;
}

extern "C" void kernel_launch(void* const* d_in, const int* in_sizes, int n_in,
                              void* d_out, int out_size, void* d_ws, size_t ws_size,
                              hipStream_t stream)
{
  const float* x      = (const float*)d_in[0];
  const float* pos    = (const float*)d_in[1];
  const float* w_q0   = (const float*)d_in[2];
  const float* w_q1   = (const float*)d_in[3];
  const float* w_kb1  = (const float*)d_in[4];
  const float* w_kb2  = (const float*)d_in[5];
  const float* w_vb1  = (const float*)d_in[6];
  const float* w_vb2  = (const float*)d_in[7];
  const float* w_sim0 = (const float*)d_in[8];
  const float* w_sim1 = (const float*)d_in[9];
  const int*   eidx   = (const int*)d_in[10];
  const int* esrc = eidx;
  const int* edst = eidx + NE;
  float* out = (float*)d_out;

  float* ws      = (float*)d_ws;
  float* geom    = ws;                               // NE*4
  float* qs0     = geom + (size_t)NE * 4;            // NN*8
  float* qs1     = qs0 + NN * 8;                     // NN*12
  float* logits  = qs1 + NN * 12;                    // NE
  float* exb     = logits + NE;                      // NE
  float* nodeF   = exb + NE;                         // NN*128
  float* W1vt    = nodeF + (size_t)NN * 128;         // 1024
  float* W1kt    = W1vt + 1024;                      // 1024
  int*   deni    = (int*)(W1kt + 1024);              // NN
  unsigned* mkey = (unsigned*)(deni + NN);           // NN
  int*   outi    = (int*)(mkey + NN);                // NN*20
  unsigned* hv2  = (unsigned*)(outi + NN * 20);      // 16*NE dwords
  unsigned short* Wtv = (unsigned short*)(hv2 + (size_t)16 * NE); // 640*32

  // zero deni + mkey + outi (contiguous, 22*NN ints)
  hipMemsetAsync(deni, 0, (size_t)(NN * 22) * sizeof(int), stream);

  const int eb = (NE + 255) / 256;   // 625
  k_setup<<<dim3(120), dim3(256), 0, stream>>>(
      w_vb1, w_vb2, w_kb1, x, w_q0, w_q1, w_sim0, w_sim1,
      W1vt, W1kt, Wtv, qs0, qs1);
  k_nodeF<<<dim3(1250), dim3(256), 0, stream>>>(
      x, w_kb2, qs0, qs1, nodeF);
  k_edgelogit<<<dim3(eb), dim3(256), 0, stream>>>(
      pos, esrc, edst, W1vt, W1kt, nodeF, hv2, geom, logits, mkey);
  k_den<<<dim3(eb), dim3(256), 0, stream>>>(logits, esrc, mkey, exb, deni);
  k_tpv<<<dim3(NE / 64), dim3(256), 0, stream>>>(
      hv2, Wtv, x, geom, esrc, edst, exb, deni, outi);
  k_out<<<dim3((NN * 20 + 255) / 256), dim3(256), 0, stream>>>(outi, out);
}

// Round 12
// 188.471 us; speedup vs baseline: 1.2578x; 1.0120x over previous
//
#include <hip/hip_runtime.h>
#include <hip/hip_fp16.h>
#include <math.h>

#define NN 10000
#define NE 160000

typedef _Float16 half8 __attribute__((ext_vector_type(8)));
typedef __attribute__((ext_vector_type(4))) float f32x4;

constexpr float SQRT3f    = 1.7320508075688772f;
constexpr float ISQRT3    = 0.57735026918962576f;
constexpr float ISQRT32   = 0.17677669529663687f;   // 1/sqrt(32)
constexpr float C_TP      = 0.14433756729740645f;   // 1/sqrt(48)
constexpr float CSIM      = 0.11180339887498949f;   // 1/sqrt(80)
constexpr float PREB      = 5.0596442562694074f;    // sqrt(2/2.5)*sqrt(32)
constexpr float PI_OVER_R = 1.2566370614359172f;    // pi/2.5
constexpr float INV_RMAX  = 0.4f;
constexpr float HKSC      = C_TP * ISQRT32;
constexpr float DEN_SCALE = 16777216.0f;            // 2^24
constexpr float DEN_INV   = 1.0f / 16777216.0f;
constexpr float OUT_SCALE = 8388608.0f;             // 2^23
constexpr float OUT_INV   = 1.0f / 8388608.0f;

__device__ __forceinline__ unsigned fkey(float f) {
  unsigned u = __float_as_uint(f);
  return (u & 0x80000000u) ? ~u : (u | 0x80000000u);
}
__device__ __forceinline__ float funkey(unsigned k) {
  return (k & 0x80000000u) ? __uint_as_float(k ^ 0x80000000u)
                           : __uint_as_float(~k);
}
__device__ __forceinline__ unsigned short f2h(float f) {
  return __half_as_ushort(__float2half(f));
}

// w-major repacked column -> original W2 column. n in [0,640).
__device__ __forceinline__ int origcol(int n) {
  if (n >= 576) return 512 + (n - 576);
  int w = n / 48, u = n % 48;
  if (w < 8) return (u < 32) ? (u * 8 + w) : (256 + (u - 32) * 8 + w);
  return (u < 32) ? (384 + u * 4 + (w - 8)) : -1;
}

// ---- K0: fused setup: weight prep (blocks 0..79) + node queries (80..119) ----
__global__ void __launch_bounds__(256) k_setup(
    const float* __restrict__ w_vb1, const float* __restrict__ w_vb2,
    const float* __restrict__ w_kb1,
    const float* __restrict__ x, const float* __restrict__ w_q0,
    const float* __restrict__ w_q1, const float* __restrict__ w_sim0,
    const float* __restrict__ w_sim1,
    float* __restrict__ W1vt, float* __restrict__ W1kt,
    unsigned short* __restrict__ Wtv,
    float* __restrict__ qs0, float* __restrict__ qs1)
{
  if (blockIdx.x < 80) {
    int tid = blockIdx.x * 256 + threadIdx.x;
    if (tid < 640 * 32) {
      int n = tid >> 5, h = tid & 31;
      int oc = origcol(n);
      float v = (oc >= 0) ? w_vb2[h * 576 + oc] : 0.0f;
      Wtv[n * 32 + h] = f2h(v);
    }
    if (tid < 1024) {
      int h = tid >> 5, n2 = tid & 31;
      W1vt[h * 32 + n2] = w_vb1[n2 * 32 + h];
    } else if (tid < 2048) {
      int j = tid - 1024;
      int h = j >> 5, n2 = j & 31;
      W1kt[h * 32 + n2] = w_kb1[n2 * 32 + h];
    }
    return;
  }
  int n = (blockIdx.x - 80) * 256 + threadIdx.x;
  if (n >= NN) return;
  float x0[32], x1f[48];
  const float4* xr = (const float4*)(x + 80 * n);
#pragma unroll
  for (int i = 0; i < 8; ++i) {
    float4 v = xr[i];
    x0[4*i]=v.x; x0[4*i+1]=v.y; x0[4*i+2]=v.z; x0[4*i+3]=v.w;
  }
#pragma unroll
  for (int i = 0; i < 12; ++i) {
    float4 v = xr[8 + i];
    x1f[4*i]=v.x; x1f[4*i+1]=v.y; x1f[4*i+2]=v.z; x1f[4*i+3]=v.w;
  }
  float q0[8];
#pragma unroll
  for (int w = 0; w < 8; ++w) {
    float a = 0.f;
#pragma unroll
    for (int u = 0; u < 32; ++u) a = fmaf(x0[u], w_q0[u * 8 + w], a);
    q0[w] = a * ISQRT32;
  }
  float q1[12];
#pragma unroll
  for (int w = 0; w < 4; ++w)
#pragma unroll
    for (int m = 0; m < 3; ++m) {
      float a = 0.f;
#pragma unroll
      for (int u = 0; u < 16; ++u) a = fmaf(x1f[3*u+m], w_q1[u*4+w], a);
      q1[w * 3 + m] = a * 0.25f;
    }
#pragma unroll
  for (int v = 0; v < 8; ++v) {
    float a = 0.f;
#pragma unroll
    for (int u = 0; u < 8; ++u) a = fmaf(w_sim0[u * 8 + v], q0[u], a);
    qs0[n * 8 + v] = CSIM * a;
  }
#pragma unroll
  for (int v = 0; v < 4; ++v)
#pragma unroll
    for (int m = 0; m < 3; ++m) {
      float a = 0.f;
#pragma unroll
      for (int u = 0; u < 4; ++u) a = fmaf(w_sim1[u*4+v], q1[u*3+m], a);
      qs1[n * 12 + v * 3 + m] = (CSIM * ISQRT3) * a;
    }
}

// ---- K2a: per-(node,h) hoisted logit tensors; both halves in one launch ----
__global__ void __launch_bounds__(256) k_nodeF(
    const float* __restrict__ x, const float* __restrict__ w_kb2,
    const float* __restrict__ qs0g, const float* __restrict__ qs1g,
    float* __restrict__ nodeF)
{
  __shared__ float W2f[16 * 577];
  __shared__ float ndl[16][100];

  const int tid = threadIdx.x;
  const int HALF = (blockIdx.x >= 625) ? 1 : 0;
  const int nb = (blockIdx.x - HALF * 625) * 16;

#pragma unroll
  for (int i = 0; i < 36; ++i) {
    int idx = i * 256 + tid;
    int row = idx / 576, col = idx - row * 576;
    W2f[row * 577 + col] = w_kb2[(HALF * 16 + row) * 576 + col];
  }
  for (int j = tid; j < 1600; j += 256) {
    int nn = j / 100, jj = j - nn * 100;
    int n = nb + nn;
    float v;
    if (jj < 80)      v = x[80 * n + jj];
    else if (jj < 88) v = qs0g[8 * n + (jj - 80)];
    else              v = qs1g[12 * n + (jj - 88)];
    ndl[nn][jj] = v;
  }
  __syncthreads();

  const int nn = tid >> 4, hh = tid & 15;
  const float* Wh = W2f + hh * 577;
  const float* nd = ndl[nn];

  float t14 = 0.f;
#pragma unroll
  for (int a = 0; a < 32; ++a) {
    float tmp = 0.f;
#pragma unroll
    for (int v = 0; v < 8; ++v) tmp = fmaf(Wh[a * 8 + v], nd[80 + v], tmp);
    t14 = fmaf(tmp, nd[a], t14);
  }
#pragma unroll
  for (int a = 0; a < 16; ++a)
#pragma unroll
    for (int v = 0; v < 4; ++v) {
      float dotv = fmaf(nd[32 + 3*a], nd[88 + 3*v],
                   fmaf(nd[32 + 3*a + 1], nd[88 + 3*v + 1],
                        nd[32 + 3*a + 2] * nd[88 + 3*v + 2]));
      t14 = fmaf(Wh[512 + a * 4 + v], dotv, t14);
    }

  float F0 = 0.f, F1 = 0.f, F2 = 0.f;
#pragma unroll
  for (int a = 0; a < 16; ++a) {
    float q = 0.f;
#pragma unroll
    for (int v = 0; v < 8; ++v) q = fmaf(Wh[256 + a * 8 + v], nd[80 + v], q);
    F0 = fmaf(q, nd[32 + 3*a],     F0);
    F1 = fmaf(q, nd[32 + 3*a + 1], F1);
    F2 = fmaf(q, nd[32 + 3*a + 2], F2);
  }
  F0 *= ISQRT3; F1 *= ISQRT3; F2 *= ISQRT3;
#pragma unroll
  for (int v = 0; v < 4; ++v) {
    float rr = 0.f;
#pragma unroll
    for (int a = 0; a < 32; ++a) rr = fmaf(Wh[384 + a * 4 + v], nd[a], rr);
    F0 = fmaf(rr, nd[88 + 3*v],     F0);
    F1 = fmaf(rr, nd[88 + 3*v + 1], F1);
    F2 = fmaf(rr, nd[88 + 3*v + 2], F2);
  }

  const int n = nb + nn, h = HALF * 16 + hh;
  *(float4*)(nodeF + (size_t)(n * 32 + h) * 4) = make_float4(t14, F0, F1, F2);
}

// ---- fused per-edge (round-10 proven): geometry + bessel + fp16 hv + logits ----
__global__ void __launch_bounds__(256) k_edgelogit(
    const float* __restrict__ pos,
    const int* __restrict__ esrc, const int* __restrict__ edst,
    const float* __restrict__ W1vt, const float* __restrict__ W1kt,
    const float* __restrict__ nodeF,
    unsigned* __restrict__ hv2, float* __restrict__ geom,
    float* __restrict__ logits, unsigned* __restrict__ mkey)
{
  int e = blockIdx.x * 256 + threadIdx.x;
  if (e >= NE) return;
  int s = esrc[e], d = edst[e];
  float vx = pos[3*s]   - pos[3*d];
  float vy = pos[3*s+1] - pos[3*d+1];
  float vz = pos[3*s+2] - pos[3*d+2];
  float r = sqrtf(fmaf(vx, vx, fmaf(vy, vy, vz * vz)) + 1e-24f);
  float inv_r = 1.0f / r;

  float rb[32];
  {
    float sn, cth;
    sincosf(PI_OVER_R * r, &sn, &cth);
    float twoc = 2.0f * cth, pre = PREB * inv_r, snm1 = 0.0f;
#pragma unroll
    for (int n = 0; n < 32; ++n) {
      rb[n] = pre * sn;
      float t = fmaf(twoc, sn, -snm1);
      snm1 = sn; sn = t;
    }
  }
  float Yx = SQRT3f * vx * inv_r, Yy = SQRT3f * vy * inv_r, Yz = SQRT3f * vz * inv_r;
  float tc = 10.0f * (1.0f - r * INV_RMAX);
  float cut = (tc > 0.0f) ? __expf(-1.0f / tc) : 0.0f;
  *(float4*)(geom + 4 * e) = make_float4(Yx, Yy, Yz, cut);

  const float4* nf = (const float4*)(nodeF) + (size_t)s * 32;
  float sim = 0.f;
#pragma unroll 1
  for (int h2 = 0; h2 < 16; ++h2) {
    const float* wv0 = W1vt + (2 * h2) * 32;   // wave-uniform -> s_load
    const float* wv1 = wv0 + 32;
    const float* wk0 = W1kt + (2 * h2) * 32;
    const float* wk1 = wk0 + 32;
    float av0 = 0.f, av1 = 0.f, ak0 = 0.f, ak1 = 0.f;
#pragma unroll
    for (int n = 0; n < 32; ++n) {
      float rn = rb[n];
      av0 = fmaf(rn, wv0[n], av0);
      av1 = fmaf(rn, wv1[n], av1);
      ak0 = fmaf(rn, wk0[n], ak0);
      ak1 = fmaf(rn, wk1[n], ak1);
    }
    av0 *= ISQRT32; av1 *= ISQRT32; ak0 *= ISQRT32; ak1 *= ISQRT32;
    float hv0 = av0 / (1.0f + __expf(-av0)) * HKSC;
    float hv1 = av1 / (1.0f + __expf(-av1)) * HKSC;
    hv2[(size_t)h2 * NE + e] = (unsigned)f2h(hv0) | ((unsigned)f2h(hv1) << 16);
    float hk0 = ak0 / (1.0f + __expf(-ak0)) * HKSC;
    float hk1 = ak1 / (1.0f + __expf(-ak1)) * HKSC;
    float4 f0 = nf[2 * h2], f1 = nf[2 * h2 + 1];
    float S0 = fmaf(f0.y, Yx, fmaf(f0.z, Yy, fmaf(f0.w, Yz, f0.x)));
    float S1 = fmaf(f1.y, Yx, fmaf(f1.z, Yy, fmaf(f1.w, Yz, f1.x)));
    sim = fmaf(hk0, S0, fmaf(hk1, S1, sim));
  }
  float lg = cut * sim;
  logits[e] = lg;
  atomicMax(mkey + s, fkey(lg));
}

// ---- softmax denominator (int fixed-point, deterministic) ----
__global__ void __launch_bounds__(256) k_den(
    const float* __restrict__ logits, const int* __restrict__ esrc,
    const unsigned* __restrict__ mkey,
    float* __restrict__ exb, int* __restrict__ deni)
{
  int e = blockIdx.x * 256 + threadIdx.x;
  if (e >= NE) return;
  int s = esrc[e];
  float m = funkey(mkey[s]);
  float ex = expf(logits[e] - m);
  exb[e] = ex;
  atomicAdd(&deni[s], __float2int_rn(ex * DEN_SCALE));
}

// ---- K2v: round-10 MFMA v-path + forced 128-VGPR + padded (swizzle-free)
// conflict-fix: tile rows padded 4->5 uint4 so b128 reads spread 8 slots. ----
__global__ void __launch_bounds__(256, 4) k_tpv(
    const unsigned* __restrict__ hv2, const unsigned short* __restrict__ Wtv,
    const float* __restrict__ x, const float* __restrict__ geom,
    const int* __restrict__ esrc, const int* __restrict__ edst,
    const float* __restrict__ exb, const int* __restrict__ deni,
    int* __restrict__ outi)
{
  __shared__ __align__(16) uint4  wlds4[36 * 16 * 5];  // padded rows, 46080 B
  __shared__ __align__(16) float g_lds[4][16 * 52];    // x0 | xdYs
  __shared__ __align__(16) float x1_lds[4][16 * 52];   // x1 (48 floats)

  const int l = threadIdx.x & 63, wv = threadIdx.x >> 6;
  const int tile = blockIdx.x * 4 + wv;
  const int G = l >> 4, c = l & 15;
  const int ebase = tile * 16;

  // stage main-tile weights (block-cooperative), remapped into padded rows
  const uint4* Wt4 = (const uint4*)Wtv;
#pragma unroll
  for (int i = 0; i < 9; ++i) {
    int chunk = i * 256 + threadIdx.x;            // 0..2303
    int t = chunk >> 6, rem = chunk & 63;
    int cc = rem >> 2, gg = rem & 3;
    wlds4[(t * 16 + cc) * 5 + gg] = Wt4[chunk];
  }

  // stage x rows: 16 edges x 20 float4 (x0 -> g_lds, x1 -> x1_lds)
#pragma unroll
  for (int i = 0; i < 5; ++i) {
    int idx = i * 64 + l;
    int ee = idx / 20, q = idx - 20 * ee;
    int ss = esrc[ebase + ee];
    float4 v = *(const float4*)(x + 80 * ss + 4 * q);
    if (q < 8)
      *(float4*)(&g_lds[wv][ee * 52 + 4 * q]) = v;
    else
      *(float4*)(&x1_lds[wv][ee * 52 + 4 * q - 32]) = v;
  }

  // xdYs -> g_lds cols 32..47
  {
    int ee = l >> 2, ug = l & 3;
    int ss = esrc[ebase + ee];
    float4 gm = *(const float4*)(geom + 4 * (ebase + ee));
    const float* xp = x + 80 * ss + 32 + 12 * ug;
    float4 p0 = *(const float4*)(xp);
    float4 p1 = *(const float4*)(xp + 4);
    float4 p2 = *(const float4*)(xp + 8);
    float4 o;
    o.x = ISQRT3 * fmaf(p0.x, gm.x, fmaf(p0.y, gm.y, p0.z * gm.z));
    o.y = ISQRT3 * fmaf(p0.w, gm.x, fmaf(p1.x, gm.y, p1.y * gm.z));
    o.z = ISQRT3 * fmaf(p1.z, gm.x, fmaf(p1.w, gm.y, p2.x * gm.z));
    o.w = ISQRT3 * fmaf(p2.y, gm.x, fmaf(p2.z, gm.y, p2.w * gm.z));
    *(float4*)(&g_lds[wv][ee * 52 + 32 + 4 * ug]) = o;
  }

  // A fragment: hv[edge ebase+c][h=8G..8G+7] via 4 coalesced dwords
  union { unsigned u[4]; half8 h8; } ua;
#pragma unroll
  for (int j = 0; j < 4; ++j)
    ua.u[j] = hv2[(size_t)(4 * G + j) * NE + ebase + c];
  half8 a8 = ua.h8;

  __syncthreads();

  // tail-tile B fragments from global (L2-resident), after the barrier
  half8 bt[4];
#pragma unroll
  for (int t = 0; t < 4; ++t)
    bt[t] = *(const half8*)(Wtv + ((36 + t) * 16 + c) * 32 + 8 * G);

  float vacc[4][12];
#pragma unroll
  for (int r = 0; r < 4; ++r)
#pragma unroll
    for (int w = 0; w < 12; ++w) vacc[r][w] = 0.0f;
  float ot1[4][3];
#pragma unroll
  for (int r = 0; r < 4; ++r) { ot1[r][0]=0.f; ot1[r][1]=0.f; ot1[r][2]=0.f; }

  const f32x4 zero4 = {0.f, 0.f, 0.f, 0.f};
  // 36 main tiles, B from LDS (padded rows -> 2-way max conflict)
#pragma unroll
  for (int t = 0; t < 36; ++t) {
    union { uint4 u; half8 h; } cvt;
    cvt.u = wlds4[(t * 16 + c) * 5 + G];
    f32x4 dd = __builtin_amdgcn_mfma_f32_16x16x32_f16(a8, cvt.h, zero4, 0, 0, 0);
    const int w = t / 3, u0 = (t % 3) * 16;
#pragma unroll
    for (int r = 0; r < 4; ++r)
      vacc[r][w] = fmaf(dd[r], g_lds[wv][(4 * G + r) * 52 + u0 + c], vacc[r][w]);
  }
  // 4 tail tiles (10-path): lane-local epilogue
#pragma unroll
  for (int t = 0; t < 4; ++t) {
    f32x4 dd = __builtin_amdgcn_mfma_f32_16x16x32_f16(a8, bt[t], zero4, 0, 0, 0);
    const int u = 4 * t + (c >> 2);
#pragma unroll
    for (int r = 0; r < 4; ++r) {
      const float* xp = &x1_lds[wv][(4 * G + r) * 52 + 3 * u];
      ot1[r][0] = fmaf(dd[r], xp[0], ot1[r][0]);
      ot1[r][1] = fmaf(dd[r], xp[1], ot1[r][1]);
      ot1[r][2] = fmaf(dd[r], xp[2], ot1[r][2]);
    }
  }

  // butterfly over the 16 u-lanes
#pragma unroll
  for (int m = 1; m < 16; m <<= 1)
#pragma unroll
    for (int r = 0; r < 4; ++r)
#pragma unroll
      for (int w = 0; w < 12; ++w)
        vacc[r][w] += __shfl_xor(vacc[r][w], m);
  // ot1: reduce the u-quarter bits
#pragma unroll
  for (int m = 4; m < 16; m <<= 1)
#pragma unroll
    for (int r = 0; r < 4; ++r)
#pragma unroll
      for (int k = 0; k < 3; ++k)
        ot1[r][k] += __shfl_xor(ot1[r][k], m);

  // lane c keeps column w==c
  float treg[4] = {0.f, 0.f, 0.f, 0.f};
#pragma unroll
  for (int w = 0; w < 12; ++w)
    if (c == w) {
#pragma unroll
      for (int r = 0; r < 4; ++r) treg[r] = vacc[r][w];
    }

  int sr[4], dst[4]; float4 g4[4]; float a_[4];
#pragma unroll
  for (int r = 0; r < 4; ++r) {
    int eg = ebase + 4 * G + r;
    sr[r] = esrc[eg];
    dst[r] = edst[eg];
    g4[r] = *(const float4*)(geom + 4 * eg);
    float denf = (float)deni[sr[r]] * DEN_INV;
    a_[r] = sqrtf(fmaxf(exb[eg] / denf, 0.f)) * 0.03125f;
  }
  float s01w[4];
#pragma unroll
  for (int r = 0; r < 4; ++r) s01w[r] = __shfl_xor(treg[r], 8);
  if (c < 8) {
#pragma unroll
    for (int r = 0; r < 4; ++r)
      atomicAdd(outi + 20 * dst[r] + c,
                __float2int_rn(a_[r] * treg[r] * OUT_SCALE));
  }
  if (c < 4) {
#pragma unroll
    for (int r = 0; r < 4; ++r) {
      float vx_ = fmaf(s01w[r], g4[r].x, ot1[r][0]);
      float vy_ = fmaf(s01w[r], g4[r].y, ot1[r][1]);
      float vz_ = fmaf(s01w[r], g4[r].z, ot1[r][2]);
      atomicAdd(outi + 20 * dst[r] + 8 + 3 * c + 0,
                __float2int_rn(a_[r] * vx_ * OUT_SCALE));
      atomicAdd(outi + 20 * dst[r] + 8 + 3 * c + 1,
                __float2int_rn(a_[r] * vy_ * OUT_SCALE));
      atomicAdd(outi + 20 * dst[r] + 8 + 3 * c + 2,
                __float2int_rn(a_[r] * vz_ * OUT_SCALE));
    }
  }
}

// ---- final int -> float conversion ----
__global__ void __launch_bounds__(256) k_out(
    const int* __restrict__ outi, float* __restrict__ out)
{
  int i = blockIdx.x * 256 + threadIdx.x;
  if (i < NN * 20) out[i] = (float)outi[i] * OUT_INV;
}

extern "C" void kernel_launch(void* const* d_in, const int* in_sizes, int n_in,
                              void* d_out, int out_size, void* d_ws, size_t ws_size,
                              hipStream_t stream)
{
  const float* x      = (const float*)d_in[0];
  const float* pos    = (const float*)d_in[1];
  const float* w_q0   = (const float*)d_in[2];
  const float* w_q1   = (const float*)d_in[3];
  const float* w_kb1  = (const float*)d_in[4];
  const float* w_kb2  = (const float*)d_in[5];
  const float* w_vb1  = (const float*)d_in[6];
  const float* w_vb2  = (const float*)d_in[7];
  const float* w_sim0 = (const float*)d_in[8];
  const float* w_sim1 = (const float*)d_in[9];
  const int*   eidx   = (const int*)d_in[10];
  const int* esrc = eidx;
  const int* edst = eidx + NE;
  float* out = (float*)d_out;

  float* ws      = (float*)d_ws;
  float* geom    = ws;                               // NE*4
  float* qs0     = geom + (size_t)NE * 4;            // NN*8
  float* qs1     = qs0 + NN * 8;                     // NN*12
  float* logits  = qs1 + NN * 12;                    // NE
  float* exb     = logits + NE;                      // NE
  float* nodeF   = exb + NE;                         // NN*128
  float* W1vt    = nodeF + (size_t)NN * 128;         // 1024
  float* W1kt    = W1vt + 1024;                      // 1024
  int*   deni    = (int*)(W1kt + 1024);              // NN
  unsigned* mkey = (unsigned*)(deni + NN);           // NN
  int*   outi    = (int*)(mkey + NN);                // NN*20
  unsigned* hv2  = (unsigned*)(outi + NN * 20);      // 16*NE dwords
  unsigned short* Wtv = (unsigned short*)(hv2 + (size_t)16 * NE); // 640*32

  // zero deni + mkey + outi (contiguous, 22*NN ints)
  hipMemsetAsync(deni, 0, (size_t)(NN * 22) * sizeof(int), stream);

  const int eb = (NE + 255) / 256;   // 625
  k_setup<<<dim3(120), dim3(256), 0, stream>>>(
      w_vb1, w_vb2, w_kb1, x, w_q0, w_q1, w_sim0, w_sim1,
      W1vt, W1kt, Wtv, qs0, qs1);
  k_nodeF<<<dim3(1250), dim3(256), 0, stream>>>(
      x, w_kb2, qs0, qs1, nodeF);
  k_edgelogit<<<dim3(eb), dim3(256), 0, stream>>>(
      pos, esrc, edst, W1vt, W1kt, nodeF, hv2, geom, logits, mkey);
  k_den<<<dim3(eb), dim3(256), 0, stream>>>(logits, esrc, mkey, exb, deni);
  k_tpv<<<dim3(NE / 64), dim3(256), 0, stream>>>(
      hv2, Wtv, x, geom, esrc, edst, exb, deni, outi);
  k_out<<<dim3((NN * 20 + 255) / 256), dim3(256), 0, stream>>>(outi, out);
}

// Round 13
// 188.121 us; speedup vs baseline: 1.2601x; 1.0019x over previous
//
#include <hip/hip_runtime.h>
#include <hip/hip_fp16.h>
#include <math.h>

#define NN 10000
#define NE 160000

typedef _Float16 half8 __attribute__((ext_vector_type(8)));
typedef __attribute__((ext_vector_type(4))) float f32x4;

constexpr float SQRT3f    = 1.7320508075688772f;
constexpr float ISQRT3    = 0.57735026918962576f;
constexpr float ISQRT32   = 0.17677669529663687f;   // 1/sqrt(32)
constexpr float C_TP      = 0.14433756729740645f;   // 1/sqrt(48)
constexpr float CSIM      = 0.11180339887498949f;   // 1/sqrt(80)
constexpr float PREB      = 5.0596442562694074f;    // sqrt(2/2.5)*sqrt(32)
constexpr float PI_OVER_R = 1.2566370614359172f;    // pi/2.5
constexpr float INV_RMAX  = 0.4f;
constexpr float HKSC      = C_TP * ISQRT32;
constexpr float DEN_SCALE = 16777216.0f;            // 2^24
constexpr float DEN_INV   = 1.0f / 16777216.0f;
constexpr float OUT_SCALE = 8388608.0f;             // 2^23
constexpr float OUT_INV   = 1.0f / 8388608.0f;

__device__ __forceinline__ unsigned fkey(float f) {
  unsigned u = __float_as_uint(f);
  return (u & 0x80000000u) ? ~u : (u | 0x80000000u);
}
__device__ __forceinline__ float funkey(unsigned k) {
  return (k & 0x80000000u) ? __uint_as_float(k ^ 0x80000000u)
                           : __uint_as_float(~k);
}
__device__ __forceinline__ unsigned short f2h(float f) {
  return __half_as_ushort(__float2half(f));
}

// w-major repacked column -> original W2 column. n in [0,640).
__device__ __forceinline__ int origcol(int n) {
  if (n >= 576) return 512 + (n - 576);
  int w = n / 48, u = n % 48;
  if (w < 8) return (u < 32) ? (u * 8 + w) : (256 + (u - 32) * 8 + w);
  return (u < 32) ? (384 + u * 4 + (w - 8)) : -1;
}

// ---- K0: fused setup: weight prep (blocks 0..79) + node queries (80..119) ----
__global__ void __launch_bounds__(256) k_setup(
    const float* __restrict__ w_vb1, const float* __restrict__ w_vb2,
    const float* __restrict__ w_kb1,
    const float* __restrict__ x, const float* __restrict__ w_q0,
    const float* __restrict__ w_q1, const float* __restrict__ w_sim0,
    const float* __restrict__ w_sim1,
    float* __restrict__ W1vt, float* __restrict__ W1kt,
    unsigned short* __restrict__ Wtv,
    float* __restrict__ qs0, float* __restrict__ qs1)
{
  if (blockIdx.x < 80) {
    int tid = blockIdx.x * 256 + threadIdx.x;
    if (tid < 640 * 32) {
      int n = tid >> 5, h = tid & 31;
      int oc = origcol(n);
      float v = (oc >= 0) ? w_vb2[h * 576 + oc] : 0.0f;
      Wtv[n * 32 + h] = f2h(v);
    }
    if (tid < 1024) {
      int h = tid >> 5, n2 = tid & 31;
      W1vt[h * 32 + n2] = w_vb1[n2 * 32 + h];
    } else if (tid < 2048) {
      int j = tid - 1024;
      int h = j >> 5, n2 = j & 31;
      W1kt[h * 32 + n2] = w_kb1[n2 * 32 + h];
    }
    return;
  }
  int n = (blockIdx.x - 80) * 256 + threadIdx.x;
  if (n >= NN) return;
  float x0[32], x1f[48];
  const float4* xr = (const float4*)(x + 80 * n);
#pragma unroll
  for (int i = 0; i < 8; ++i) {
    float4 v = xr[i];
    x0[4*i]=v.x; x0[4*i+1]=v.y; x0[4*i+2]=v.z; x0[4*i+3]=v.w;
  }
#pragma unroll
  for (int i = 0; i < 12; ++i) {
    float4 v = xr[8 + i];
    x1f[4*i]=v.x; x1f[4*i+1]=v.y; x1f[4*i+2]=v.z; x1f[4*i+3]=v.w;
  }
  float q0[8];
#pragma unroll
  for (int w = 0; w < 8; ++w) {
    float a = 0.f;
#pragma unroll
    for (int u = 0; u < 32; ++u) a = fmaf(x0[u], w_q0[u * 8 + w], a);
    q0[w] = a * ISQRT32;
  }
  float q1[12];
#pragma unroll
  for (int w = 0; w < 4; ++w)
#pragma unroll
    for (int m = 0; m < 3; ++m) {
      float a = 0.f;
#pragma unroll
      for (int u = 0; u < 16; ++u) a = fmaf(x1f[3*u+m], w_q1[u*4+w], a);
      q1[w * 3 + m] = a * 0.25f;
    }
#pragma unroll
  for (int v = 0; v < 8; ++v) {
    float a = 0.f;
#pragma unroll
    for (int u = 0; u < 8; ++u) a = fmaf(w_sim0[u * 8 + v], q0[u], a);
    qs0[n * 8 + v] = CSIM * a;
  }
#pragma unroll
  for (int v = 0; v < 4; ++v)
#pragma unroll
    for (int m = 0; m < 3; ++m) {
      float a = 0.f;
#pragma unroll
      for (int u = 0; u < 4; ++u) a = fmaf(w_sim1[u*4+v], q1[u*3+m], a);
      qs1[n * 12 + v * 3 + m] = (CSIM * ISQRT3) * a;
    }
}

// ---- K2a: per-(node,h) hoisted logit tensors; both halves in one launch ----
__global__ void __launch_bounds__(256) k_nodeF(
    const float* __restrict__ x, const float* __restrict__ w_kb2,
    const float* __restrict__ qs0g, const float* __restrict__ qs1g,
    float* __restrict__ nodeF)
{
  __shared__ float W2f[16 * 577];
  __shared__ float ndl[16][100];

  const int tid = threadIdx.x;
  const int HALF = (blockIdx.x >= 625) ? 1 : 0;
  const int nb = (blockIdx.x - HALF * 625) * 16;

#pragma unroll
  for (int i = 0; i < 36; ++i) {
    int idx = i * 256 + tid;
    int row = idx / 576, col = idx - row * 576;
    W2f[row * 577 + col] = w_kb2[(HALF * 16 + row) * 576 + col];
  }
  for (int j = tid; j < 1600; j += 256) {
    int nn = j / 100, jj = j - nn * 100;
    int n = nb + nn;
    float v;
    if (jj < 80)      v = x[80 * n + jj];
    else if (jj < 88) v = qs0g[8 * n + (jj - 80)];
    else              v = qs1g[12 * n + (jj - 88)];
    ndl[nn][jj] = v;
  }
  __syncthreads();

  const int nn = tid >> 4, hh = tid & 15;
  const float* Wh = W2f + hh * 577;
  const float* nd = ndl[nn];

  float t14 = 0.f;
#pragma unroll
  for (int a = 0; a < 32; ++a) {
    float tmp = 0.f;
#pragma unroll
    for (int v = 0; v < 8; ++v) tmp = fmaf(Wh[a * 8 + v], nd[80 + v], tmp);
    t14 = fmaf(tmp, nd[a], t14);
  }
#pragma unroll
  for (int a = 0; a < 16; ++a)
#pragma unroll
    for (int v = 0; v < 4; ++v) {
      float dotv = fmaf(nd[32 + 3*a], nd[88 + 3*v],
                   fmaf(nd[32 + 3*a + 1], nd[88 + 3*v + 1],
                        nd[32 + 3*a + 2] * nd[88 + 3*v + 2]));
      t14 = fmaf(Wh[512 + a * 4 + v], dotv, t14);
    }

  float F0 = 0.f, F1 = 0.f, F2 = 0.f;
#pragma unroll
  for (int a = 0; a < 16; ++a) {
    float q = 0.f;
#pragma unroll
    for (int v = 0; v < 8; ++v) q = fmaf(Wh[256 + a * 8 + v], nd[80 + v], q);
    F0 = fmaf(q, nd[32 + 3*a],     F0);
    F1 = fmaf(q, nd[32 + 3*a + 1], F1);
    F2 = fmaf(q, nd[32 + 3*a + 2], F2);
  }
  F0 *= ISQRT3; F1 *= ISQRT3; F2 *= ISQRT3;
#pragma unroll
  for (int v = 0; v < 4; ++v) {
    float rr = 0.f;
#pragma unroll
    for (int a = 0; a < 32; ++a) rr = fmaf(Wh[384 + a * 4 + v], nd[a], rr);
    F0 = fmaf(rr, nd[88 + 3*v],     F0);
    F1 = fmaf(rr, nd[88 + 3*v + 1], F1);
    F2 = fmaf(rr, nd[88 + 3*v + 2], F2);
  }

  const int n = nb + nn, h = HALF * 16 + hh;
  *(float4*)(nodeF + (size_t)(n * 32 + h) * 4) = make_float4(t14, F0, F1, F2);
}

// ---- fused per-edge (round-10 proven): geometry + bessel + fp16 hv + logits ----
__global__ void __launch_bounds__(256) k_edgelogit(
    const float* __restrict__ pos,
    const int* __restrict__ esrc, const int* __restrict__ edst,
    const float* __restrict__ W1vt, const float* __restrict__ W1kt,
    const float* __restrict__ nodeF,
    unsigned* __restrict__ hv2, float* __restrict__ geom,
    float* __restrict__ logits, unsigned* __restrict__ mkey)
{
  int e = blockIdx.x * 256 + threadIdx.x;
  if (e >= NE) return;
  int s = esrc[e], d = edst[e];
  float vx = pos[3*s]   - pos[3*d];
  float vy = pos[3*s+1] - pos[3*d+1];
  float vz = pos[3*s+2] - pos[3*d+2];
  float r = sqrtf(fmaf(vx, vx, fmaf(vy, vy, vz * vz)) + 1e-24f);
  float inv_r = 1.0f / r;

  float rb[32];
  {
    float sn, cth;
    sincosf(PI_OVER_R * r, &sn, &cth);
    float twoc = 2.0f * cth, pre = PREB * inv_r, snm1 = 0.0f;
#pragma unroll
    for (int n = 0; n < 32; ++n) {
      rb[n] = pre * sn;
      float t = fmaf(twoc, sn, -snm1);
      snm1 = sn; sn = t;
    }
  }
  float Yx = SQRT3f * vx * inv_r, Yy = SQRT3f * vy * inv_r, Yz = SQRT3f * vz * inv_r;
  float tc = 10.0f * (1.0f - r * INV_RMAX);
  float cut = (tc > 0.0f) ? __expf(-1.0f / tc) : 0.0f;
  *(float4*)(geom + 4 * e) = make_float4(Yx, Yy, Yz, cut);

  const float4* nf = (const float4*)(nodeF) + (size_t)s * 32;
  float sim = 0.f;
#pragma unroll 1
  for (int h2 = 0; h2 < 16; ++h2) {
    const float* wv0 = W1vt + (2 * h2) * 32;   // wave-uniform -> s_load
    const float* wv1 = wv0 + 32;
    const float* wk0 = W1kt + (2 * h2) * 32;
    const float* wk1 = wk0 + 32;
    float av0 = 0.f, av1 = 0.f, ak0 = 0.f, ak1 = 0.f;
#pragma unroll
    for (int n = 0; n < 32; ++n) {
      float rn = rb[n];
      av0 = fmaf(rn, wv0[n], av0);
      av1 = fmaf(rn, wv1[n], av1);
      ak0 = fmaf(rn, wk0[n], ak0);
      ak1 = fmaf(rn, wk1[n], ak1);
    }
    av0 *= ISQRT32; av1 *= ISQRT32; ak0 *= ISQRT32; ak1 *= ISQRT32;
    float hv0 = av0 / (1.0f + __expf(-av0)) * HKSC;
    float hv1 = av1 / (1.0f + __expf(-av1)) * HKSC;
    hv2[(size_t)h2 * NE + e] = (unsigned)f2h(hv0) | ((unsigned)f2h(hv1) << 16);
    float hk0 = ak0 / (1.0f + __expf(-ak0)) * HKSC;
    float hk1 = ak1 / (1.0f + __expf(-ak1)) * HKSC;
    float4 f0 = nf[2 * h2], f1 = nf[2 * h2 + 1];
    float S0 = fmaf(f0.y, Yx, fmaf(f0.z, Yy, fmaf(f0.w, Yz, f0.x)));
    float S1 = fmaf(f1.y, Yx, fmaf(f1.z, Yy, fmaf(f1.w, Yz, f1.x)));
    sim = fmaf(hk0, S0, fmaf(hk1, S1, sim));
  }
  float lg = cut * sim;
  logits[e] = lg;
  atomicMax(mkey + s, fkey(lg));
}

// ---- softmax denominator (int fixed-point, deterministic) ----
__global__ void __launch_bounds__(256) k_den(
    const float* __restrict__ logits, const int* __restrict__ esrc,
    const unsigned* __restrict__ mkey,
    float* __restrict__ exb, int* __restrict__ deni)
{
  int e = blockIdx.x * 256 + threadIdx.x;
  if (e >= NE) return;
  int s = esrc[e];
  float m = funkey(mkey[s]);
  float ex = expf(logits[e] - m);
  exb[e] = ex;
  atomicAdd(&deni[s], __float2int_rn(ex * DEN_SCALE));
}

// ---- K2v: round-10 MFMA v-path + forced 128-VGPR + padded (swizzle-free)
// conflict-fix: tile rows padded 4->5 uint4 so b128 reads spread 8 slots. ----
__global__ void __launch_bounds__(256, 4) k_tpv(
    const unsigned* __restrict__ hv2, const unsigned short* __restrict__ Wtv,
    const float* __restrict__ x, const float* __restrict__ geom,
    const int* __restrict__ esrc, const int* __restrict__ edst,
    const float* __restrict__ exb, const int* __restrict__ deni,
    int* __restrict__ outi)
{
  __shared__ __align__(16) uint4  wlds4[36 * 16 * 5];  // padded rows, 46080 B
  __shared__ __align__(16) float g_lds[4][16 * 52];    // x0 | xdYs
  __shared__ __align__(16) float x1_lds[4][16 * 52];   // x1 (48 floats)

  const int l = threadIdx.x & 63, wv = threadIdx.x >> 6;
  const int tile = blockIdx.x * 4 + wv;
  const int G = l >> 4, c = l & 15;
  const int ebase = tile * 16;

  // stage main-tile weights (block-cooperative), remapped into padded rows
  const uint4* Wt4 = (const uint4*)Wtv;
#pragma unroll
  for (int i = 0; i < 9; ++i) {
    int chunk = i * 256 + threadIdx.x;            // 0..2303
    int t = chunk >> 6, rem = chunk & 63;
    int cc = rem >> 2, gg = rem & 3;
    wlds4[(t * 16 + cc) * 5 + gg] = Wt4[chunk];
  }

  // stage x rows: 16 edges x 20 float4 (x0 -> g_lds, x1 -> x1_lds)
#pragma unroll
  for (int i = 0; i < 5; ++i) {
    int idx = i * 64 + l;
    int ee = idx / 20, q = idx - 20 * ee;
    int ss = esrc[ebase + ee];
    float4 v = *(const float4*)(x + 80 * ss + 4 * q);
    if (q < 8)
      *(float4*)(&g_lds[wv][ee * 52 + 4 * q]) = v;
    else
      *(float4*)(&x1_lds[wv][ee * 52 + 4 * q - 32]) = v;
  }

  // xdYs -> g_lds cols 32..47
  {
    int ee = l >> 2, ug = l & 3;
    int ss = esrc[ebase + ee];
    float4 gm = *(const float4*)(geom + 4 * (ebase + ee));
    const float* xp = x + 80 * ss + 32 + 12 * ug;
    float4 p0 = *(const float4*)(xp);
    float4 p1 = *(const float4*)(xp + 4);
    float4 p2 = *(const float4*)(xp + 8);
    float4 o;
    o.x = ISQRT3 * fmaf(p0.x, gm.x, fmaf(p0.y, gm.y, p0.z * gm.z));
    o.y = ISQRT3 * fmaf(p0.w, gm.x, fmaf(p1.x, gm.y, p1.y * gm.z));
    o.z = ISQRT3 * fmaf(p1.z, gm.x, fmaf(p1.w, gm.y, p2.x * gm.z));
    o.w = ISQRT3 * fmaf(p2.y, gm.x, fmaf(p2.z, gm.y, p2.w * gm.z));
    *(float4*)(&g_lds[wv][ee * 52 + 32 + 4 * ug]) = o;
  }

  // A fragment: hv[edge ebase+c][h=8G..8G+7] via 4 coalesced dwords
  union { unsigned u[4]; half8 h8; } ua;
#pragma unroll
  for (int j = 0; j < 4; ++j)
    ua.u[j] = hv2[(size_t)(4 * G + j) * NE + ebase + c];
  half8 a8 = ua.h8;

  __syncthreads();

  // tail-tile B fragments from global (L2-resident), after the barrier
  half8 bt[4];
#pragma unroll
  for (int t = 0; t < 4; ++t)
    bt[t] = *(const half8*)(Wtv + ((36 + t) * 16 + c) * 32 + 8 * G);

  float vacc[4][12];
#pragma unroll
  for (int r = 0; r < 4; ++r)
#pragma unroll
    for (int w = 0; w < 12; ++w) vacc[r][w] = 0.0f;
  float ot1[4][3];
#pragma unroll
  for (int r = 0; r < 4; ++r) { ot1[r][0]=0.f; ot1[r][1]=0.f; ot1[r][2]=0.f; }

  const f32x4 zero4 = {0.f, 0.f, 0.f, 0.f};
  // 36 main tiles, B from LDS (padded rows -> 2-way max conflict)
#pragma unroll
  for (int t = 0; t < 36; ++t) {
    union { uint4 u; half8 h; } cvt;
    cvt.u = wlds4[(t * 16 + c) * 5 + G];
    f32x4 dd = __builtin_amdgcn_mfma_f32_16x16x32_f16(a8, cvt.h, zero4, 0, 0, 0);
    const int w = t / 3, u0 = (t % 3) * 16;
#pragma unroll
    for (int r = 0; r < 4; ++r)
      vacc[r][w] = fmaf(dd[r], g_lds[wv][(4 * G + r) * 52 + u0 + c], vacc[r][w]);
  }
  // 4 tail tiles (10-path): lane-local epilogue
#pragma unroll
  for (int t = 0; t < 4; ++t) {
    f32x4 dd = __builtin_amdgcn_mfma_f32_16x16x32_f16(a8, bt[t], zero4, 0, 0, 0);
    const int u = 4 * t + (c >> 2);
#pragma unroll
    for (int r = 0; r < 4; ++r) {
      const float* xp = &x1_lds[wv][(4 * G + r) * 52 + 3 * u];
      ot1[r][0] = fmaf(dd[r], xp[0], ot1[r][0]);
      ot1[r][1] = fmaf(dd[r], xp[1], ot1[r][1]);
      ot1[r][2] = fmaf(dd[r], xp[2], ot1[r][2]);
    }
  }

  // butterfly over the 16 u-lanes
#pragma unroll
  for (int m = 1; m < 16; m <<= 1)
#pragma unroll
    for (int r = 0; r < 4; ++r)
#pragma unroll
      for (int w = 0; w < 12; ++w)
        vacc[r][w] += __shfl_xor(vacc[r][w], m);
  // ot1: reduce the u-quarter bits
#pragma unroll
  for (int m = 4; m < 16; m <<= 1)
#pragma unroll
    for (int r = 0; r < 4; ++r)
#pragma unroll
      for (int k = 0; k < 3; ++k)
        ot1[r][k] += __shfl_xor(ot1[r][k], m);

  // lane c keeps column w==c
  float treg[4] = {0.f, 0.f, 0.f, 0.f};
#pragma unroll
  for (int w = 0; w < 12; ++w)
    if (c == w) {
#pragma unroll
      for (int r = 0; r < 4; ++r) treg[r] = vacc[r][w];
    }

  int sr[4], dst[4]; float4 g4[4]; float a_[4];
#pragma unroll
  for (int r = 0; r < 4; ++r) {
    int eg = ebase + 4 * G + r;
    sr[r] = esrc[eg];
    dst[r] = edst[eg];
    g4[r] = *(const float4*)(geom + 4 * eg);
    float denf = (float)deni[sr[r]] * DEN_INV;
    a_[r] = sqrtf(fmaxf(exb[eg] / denf, 0.f)) * 0.03125f;
  }
  float s01w[4];
#pragma unroll
  for (int r = 0; r < 4; ++r) s01w[r] = __shfl_xor(treg[r], 8);
  if (c < 8) {
#pragma unroll
    for (int r = 0; r < 4; ++r)
      atomicAdd(outi + 20 * dst[r] + c,
                __float2int_rn(a_[r] * treg[r] * OUT_SCALE));
  }
  if (c < 4) {
#pragma unroll
    for (int r = 0; r < 4; ++r) {
      float vx_ = fmaf(s01w[r], g4[r].x, ot1[r][0]);
      float vy_ = fmaf(s01w[r], g4[r].y, ot1[r][1]);
      float vz_ = fmaf(s01w[r], g4[r].z, ot1[r][2]);
      atomicAdd(outi + 20 * dst[r] + 8 + 3 * c + 0,
                __float2int_rn(a_[r] * vx_ * OUT_SCALE));
      atomicAdd(outi + 20 * dst[r] + 8 + 3 * c + 1,
                __float2int_rn(a_[r] * vy_ * OUT_SCALE));
      atomicAdd(outi + 20 * dst[r] + 8 + 3 * c + 2,
                __float2int_rn(a_[r] * vz_ * OUT_SCALE));
    }
  }
}

// ---- final int -> float conversion ----
__global__ void __launch_bounds__(256) k_out(
    const int* __restrict__ outi, float* __restrict__ out)
{
  int i = blockIdx.x * 256 + threadIdx.x;
  if (i < NN * 20) out[i] = (float)outi[i] * OUT_INV;
}

extern "C" void kernel_launch(void* const* d_in, const int* in_sizes, int n_in,
                              void* d_out, int out_size, void* d_ws, size_t ws_size,
                              hipStream_t stream)
{
  const float* x      = (const float*)d_in[0];
  const float* pos    = (const float*)d_in[1];
  const float* w_q0   = (const float*)d_in[2];
  const float* w_q1   = (const float*)d_in[3];
  const float* w_kb1  = (const float*)d_in[4];
  const float* w_kb2  = (const float*)d_in[5];
  const float* w_vb1  = (const float*)d_in[6];
  const float* w_vb2  = (const float*)d_in[7];
  const float* w_sim0 = (const float*)d_in[8];
  const float* w_sim1 = (const float*)d_in[9];
  const int*   eidx   = (const int*)d_in[10];
  const int* esrc = eidx;
  const int* edst = eidx + NE;
  float* out = (float*)d_out;

  float* ws      = (float*)d_ws;
  float* geom    = ws;                               // NE*4
  float* qs0     = geom + (size_t)NE * 4;            // NN*8
  float* qs1     = qs0 + NN * 8;                     // NN*12
  float* logits  = qs1 + NN * 12;                    // NE
  float* exb     = logits + NE;                      // NE
  float* nodeF   = exb + NE;                         // NN*128
  float* W1vt    = nodeF + (size_t)NN * 128;         // 1024
  float* W1kt    = W1vt + 1024;                      // 1024
  int*   deni    = (int*)(W1kt + 1024);              // NN
  unsigned* mkey = (unsigned*)(deni + NN);           // NN
  int*   outi    = (int*)(mkey + NN);                // NN*20
  unsigned* hv2  = (unsigned*)(outi + NN * 20);      // 16*NE dwords
  unsigned short* Wtv = (unsigned short*)(hv2 + (size_t)16 * NE); // 640*32

  // zero deni + mkey + outi (contiguous, 22*NN ints)
  hipMemsetAsync(deni, 0, (size_t)(NN * 22) * sizeof(int), stream);

  const int eb = (NE + 255) / 256;   // 625
  k_setup<<<dim3(120), dim3(256), 0, stream>>>(
      w_vb1, w_vb2, w_kb1, x, w_q0, w_q1, w_sim0, w_sim1,
      W1vt, W1kt, Wtv, qs0, qs1);
  k_nodeF<<<dim3(1250), dim3(256), 0, stream>>>(
      x, w_kb2, qs0, qs1, nodeF);
  k_edgelogit<<<dim3(eb), dim3(256), 0, stream>>>(
      pos, esrc, edst, W1vt, W1kt, nodeF, hv2, geom, logits, mkey);
  k_den<<<dim3(eb), dim3(256), 0, stream>>>(logits, esrc, mkey, exb, deni);
  k_tpv<<<dim3(NE / 64), dim3(256), 0, stream>>>(
      hv2, Wtv, x, geom, esrc, edst, exb, deni, outi);
  k_out<<<dim3((NN * 20 + 255) / 256), dim3(256), 0, stream>>>(outi, out);
}